// Round 15
// baseline (755.175 us; speedup 1.0000x reference)
//
#include <hip/hip_runtime.h>
#include <hip/hip_bf16.h>

// Problem constants
constexpr int B_ = 32, S_ = 512, D_ = 512, H_ = 8, L_ = 4, F_ = 2048, DK_ = 64;

typedef __attribute__((ext_vector_type(8))) short short8;
typedef __attribute__((ext_vector_type(4))) float f32x4;
typedef __attribute__((ext_vector_type(16))) float f32x16;

__device__ inline unsigned short f2b(float f) {
  union { __hip_bfloat16 h; unsigned short u; } cv;
  cv.h = __float2bfloat16(f);
  return cv.u;
}
__device__ inline float b2f(unsigned short u) {
  union { unsigned int i; float f; } c;
  c.i = ((unsigned int)u) << 16;
  return c.f;
}
__device__ inline unsigned pkbf(float a, float b) {
  unsigned r;
  asm("v_cvt_pk_bf16_f32 %0, %1, %2" : "=v"(r) : "v"(a), "v"(b));
  return r;
}
__device__ inline float waveReduceSum(float v) {
  #pragma unroll
  for (int o = 32; o > 0; o >>= 1) v += __shfl_xor(v, o);
  return v;
}

// ---------------- prep: xb = bf16(q + pos), yb = bf16(qa + pos) --------------
__global__ void prep_kernel(const float4* __restrict__ q, const float4* __restrict__ qa,
                            const float4* __restrict__ pos,
                            uint2* __restrict__ xb, uint2* __restrict__ yb) {
  int i = blockIdx.x * blockDim.x + threadIdx.x;  // 2,097,152 exact
  float4 p = pos[i & 65535];
  float4 a = q[i], c = qa[i];
  uint2 px, py;
  px.x = pkbf(a.x + p.x, a.y + p.y);
  px.y = pkbf(a.z + p.z, a.w + p.w);
  py.x = pkbf(c.x + p.x, c.y + p.y);
  py.y = pkbf(c.z + p.z, c.w + p.w);
  xb[i] = px;
  yb[i] = py;
}

// ---------------- cast fp32 -> bf16 ------------------------------------------
__global__ void cast_kernel(const float4* __restrict__ src, uint2* __restrict__ dst, int n4) {
  int i = blockIdx.x * blockDim.x + threadIdx.x;
  if (i >= n4) return;
  float4 v = src[i];
  uint2 p;
  p.x = pkbf(v.x, v.y);
  p.y = pkbf(v.z, v.w);
  dst[i] = p;
}

// ---------------- 128x128 MFMA GEMM, 4-buf ring + counted vmcnt --------------
// C[M,N] = A[M,K] @ W[N,K]^T. BK=32, 4 waves (2x2 of 64x64). 64KB LDS ring
// (4 bufs x 8KB per matrix) -> 2 blocks/CU; prologue stages tiles 0-2 (12
// loads/thread in flight); per tile: wait vmcnt(8) (drains ONLY tile kt's 4
// loads, issued ~3 tiles ago), raw s_barrier, stage kt+3. Never drains to 0
// mid-loop. Proven 0-conflict swizzle; coalesced LDS-relayout epilogue.
// STORE 0: bf16 row-major (z picks Cb/Cb2, bias only z==0).
// STORE 3: dual-GEMM — z==0: A/W/bias -> Cb row-major;
//                      z==1: A2/W2/bias2 -> Cb2 vT[((b*8+h)*64+d)*512+t].
template<int RELU, int STORE>
__global__ __launch_bounds__(256, 2) void gemm128_kernel(
    const __hip_bfloat16* __restrict__ A,
    const __hip_bfloat16* __restrict__ W,
    const float* __restrict__ bias,
    const __hip_bfloat16* __restrict__ A2,
    const __hip_bfloat16* __restrict__ W2,
    const float* __restrict__ bias2,
    __hip_bfloat16* __restrict__ Cb,
    __hip_bfloat16* __restrict__ Cb2,
    int Ndim, int Kdim, int kLen)
{
  __shared__ char lds[65536];  // A: buf*8192 [0,32K); W: 32768 + buf*8192
  const int tid = threadIdx.x, wave = tid >> 6, lane = tid & 63;
  const int rl = lane & 15, gq = lane >> 4;
  const int wr = wave >> 1, wc = wave & 1;

  const int nwg = gridDim.x * gridDim.y;
  const int lin = blockIdx.y * gridDim.x + blockIdx.x;
  const int swz = (lin & 7) * (nwg >> 3) + (lin >> 3);
  const int bx = swz % gridDim.x, by = swz / gridDim.x;

  const int row0 = by * 128;
  const int col0 = bx * 128;

  const __hip_bfloat16* Ap = A;
  const __hip_bfloat16* Wp = W;
  const float* bp = bias;
  int kOff = blockIdx.z * kLen;
  if (STORE == 3) {
    kOff = 0;
    if (blockIdx.z) { Ap = A2; Wp = W2; bp = bias2; }
  }

  f32x4 acc[4][4] = {};
  const int ntiles = kLen >> 5;

  auto stage = [&](int kt) {
    const int buf = kt & 3;
    const int kbase = kOff + (kt << 5);
    #pragma unroll
    for (int r = 0; r < 2; ++r) {
      int p = r * 4096 + tid * 16;
      int R = p >> 6, c = (p >> 4) & 3;
      int gc = c ^ ((R >> 1) & 3);
      const __hip_bfloat16* srcA = Ap + (size_t)(row0 + R) * Kdim + kbase + gc * 8;
      __builtin_amdgcn_global_load_lds(
          (const __attribute__((address_space(1))) void*)srcA,
          (__attribute__((address_space(3))) void*)(lds + buf * 8192 + p), 16, 0, 0);
      const __hip_bfloat16* srcW = Wp + (size_t)(col0 + R) * Kdim + kbase + gc * 8;
      __builtin_amdgcn_global_load_lds(
          (const __attribute__((address_space(1))) void*)srcW,
          (__attribute__((address_space(3))) void*)(lds + 32768 + buf * 8192 + p), 16, 0, 0);
    }
  };

  stage(0); stage(1); stage(2);   // 12 loads/thread in flight
  for (int kt = 0; kt < ntiles; ++kt) {
    // drain only tile kt's 4 loads (issued ~3 tiles ago); keep rest in flight
    if (kt + 2 < ntiles) {
      asm volatile("s_waitcnt vmcnt(8)" ::: "memory");
    } else if (kt + 1 < ntiles) {
      asm volatile("s_waitcnt vmcnt(4)" ::: "memory");
    } else {
      asm volatile("s_waitcnt vmcnt(0)" ::: "memory");
    }
    __builtin_amdgcn_sched_barrier(0);
    __builtin_amdgcn_s_barrier();      // raw: loads stay in flight
    __builtin_amdgcn_sched_barrier(0);
    // buf (kt+3)&3 held tile kt-1: its reads finished before this barrier
    if (kt + 3 < ntiles) stage(kt + 3);

    const int abase = (kt & 3) * 8192;
    const int wbase = 32768 + (kt & 3) * 8192;
    short8 aF[4], bF[4];
    #pragma unroll
    for (int m = 0; m < 4; ++m) {
      int rr = wr * 64 + m * 16 + rl;
      aF[m] = *(const short8*)(lds + abase + rr * 64 + ((gq ^ ((rr >> 1) & 3)) << 4));
    }
    #pragma unroll
    for (int n = 0; n < 4; ++n) {
      int rr = wc * 64 + n * 16 + rl;
      bF[n] = *(const short8*)(lds + wbase + rr * 64 + ((gq ^ ((rr >> 1) & 3)) << 4));
    }
    __builtin_amdgcn_s_setprio(1);
    #pragma unroll
    for (int m = 0; m < 4; ++m)
      #pragma unroll
      for (int n = 0; n < 4; ++n)
        acc[m][n] = __builtin_amdgcn_mfma_f32_16x16x32_bf16(aF[m], bF[n], acc[m][n], 0, 0, 0);
    __builtin_amdgcn_s_setprio(0);
  }
  __syncthreads();  // all waves done with LDS before epilogue re-use

  // ---------------- coalesced epilogue (LDS re-layout) ----------------
  char* sw = lds + wave * 8192;  // per-wave 64 rows * 128B scratch (A region)
  const bool vt = (STORE == 3) && (blockIdx.z == 1);
  const bool addb = (STORE == 3) ? true : ((bias != nullptr) && (blockIdx.z == 0));
  float bvv[4];
  #pragma unroll
  for (int n = 0; n < 4; ++n)
    bvv[n] = addb ? bp[col0 + wc * 64 + n * 16 + rl] : 0.0f;

  #pragma unroll
  for (int n = 0; n < 4; ++n)
    #pragma unroll
    for (int m = 0; m < 4; ++m)
      #pragma unroll
      for (int j = 0; j < 4; ++j) {
        float val = acc[m][n][j] + bvv[n];
        if (RELU) val = fmaxf(val, 0.0f);
        int addr;
        if (vt) {
          int orow = n * 16 + rl, ocol = m * 16 + gq * 4 + j;
          addr = orow * 128 + ((ocol * 2) ^ ((orow & 7) << 4));
        } else {
          int orow = m * 16 + gq * 4 + j;
          addr = orow * 128 + (((n * 16 + rl) * 2) ^ (((orow >> 1) & 7) << 4));
        }
        *(unsigned short*)(sw + addr) = f2b(val);
      }
  asm volatile("s_waitcnt lgkmcnt(0)" ::: "memory");
  __builtin_amdgcn_sched_barrier(0);

  __hip_bfloat16* Cbd = blockIdx.z ? Cb2 : Cb;
  const int cchunk = lane & 7;
  if (vt) {
    const int bh64 = ((row0 >> 9) * 8 + (col0 >> 6) + wc) * 64;
    const int tbase = (row0 & 511) + wr * 64;
    #pragma unroll
    for (int it = 0; it < 8; ++it) {
      int d0 = it * 8 + (lane >> 3);
      uint4 vv = *(const uint4*)(sw + d0 * 128 + ((cchunk * 16) ^ ((d0 & 7) << 4)));
      *(uint4*)((char*)Cbd + ((size_t)(bh64 + d0) * 512 + tbase) * 2 + cchunk * 16) = vv;
    }
  } else {
    #pragma unroll
    for (int it = 0; it < 8; ++it) {
      int orow = it * 8 + (lane >> 3);
      uint4 vv = *(const uint4*)(sw + orow * 128 + ((cchunk * 16) ^ (((orow >> 1) & 7) << 4)));
      *(uint4*)((char*)Cbd + ((size_t)(row0 + wr * 64 + orow) * Ndim + col0 + wc * 64) * 2 +
                cchunk * 16) = vv;
    }
  }
}

// ---------------- flash attention: swapped-QK^T, in-register softmax ---------
// grid 256 = (b,h), 512 thr. Block stages K[512][64] + vT[64][512] once
// (128KB LDS, chunk-XOR swizzles), then 8 waves run barrier-free. Wave w owns
// q-tiles {w, 15-w}; swapped 32x32x16 MFMAs put q on the output COLUMN so
// softmax state is lane-scalar; P repacked in-register into PV's B-operand.
__global__ __launch_bounds__(512, 2) void fattn_kernel(
    const __hip_bfloat16* __restrict__ kq,  // [B*S, D]
    const __hip_bfloat16* __restrict__ vT,  // [(b*8+h)*64+d][t]
    const float* __restrict__ fr,           // [B*S]
    __hip_bfloat16* __restrict__ ctx)       // [B*S, D]
{
  __shared__ char lds[131072];  // K [0,64K) ck^(r&7); vT [64K,128K) ck^(d&15)
  const int tid = threadIdx.x, wave = tid >> 6, lane = tid & 63;
  const int lq = lane & 31, hi = lane >> 5;
  const int bh = blockIdx.x;
  const int b = bh >> 3, h = bh & 7;
  const size_t kqbase = ((size_t)b * S_) * D_ + h * DK_;
  const size_t vtbase = ((size_t)bh * DK_) * S_;
  const char* kg = (const char*)kq + kqbase * 2;
  const char* vg = (const char*)vT + vtbase * 2;

  #pragma unroll
  for (int i = 0; i < 8; ++i) {
    int p = i * 8192 + tid * 16;
    int r = p >> 7, ck = (p >> 4) & 7;
    __builtin_amdgcn_global_load_lds(
        (const __attribute__((address_space(1))) void*)(kg + (size_t)r * 1024 + ((ck ^ (r & 7)) << 4)),
        (__attribute__((address_space(3))) void*)(lds + p), 16, 0, 0);
  }
  #pragma unroll
  for (int i = 0; i < 8; ++i) {
    int p = i * 8192 + tid * 16;
    int d = p >> 10, ck = (p >> 4) & 63;
    __builtin_amdgcn_global_load_lds(
        (const __attribute__((address_space(1))) void*)(vg + (size_t)d * 1024 + ((ck ^ (d & 15)) << 4)),
        (__attribute__((address_space(3))) void*)(lds + 65536 + p), 16, 0, 0);
  }

  const int qia = wave, qib = 15 - wave;
  const int na = qia + 1, nb = qib + 1;
  const int sa = qia * 32 + lq, sb = qib * 32 + lq;
  const float sfa = fr[b * S_ + sa] * 0.125f;
  const float sfb = fr[b * S_ + sb] * 0.125f;

  asm volatile("s_waitcnt vmcnt(0)" ::: "memory");
  __builtin_amdgcn_sched_barrier(0);
  __builtin_amdgcn_s_barrier();

  short8 qa_[4], qb_[4];
  #pragma unroll
  for (int f = 0; f < 4; ++f) {
    qa_[f] = *(const short8*)(lds + sa * 128 + ((((f << 1) + hi) ^ (sa & 7)) << 4));
    qb_[f] = *(const short8*)(lds + sb * 128 + ((((f << 1) + hi) ^ (sb & 7)) << 4));
  }

  f32x16 oa0 = {}, oa1 = {}, ob0 = {}, ob1 = {};
  float ma = -3.0e38f, la = 0.0f, mb = -3.0e38f, lb = 0.0f;

  auto process = [&](f32x16& o0, f32x16& o1, float& m, float& l,
                     const short8* qf, int srow, float sf,
                     const short8* kb, const short8* vb0, const short8* vb1,
                     int t0) {
    f32x16 s = {};
    #pragma unroll
    for (int f = 0; f < 4; ++f)
      s = __builtin_amdgcn_mfma_f32_32x32x16_bf16(kb[f], qf[f], s, 0, 0, 0);
    float p[16];
    #pragma unroll
    for (int r = 0; r < 16; ++r) {
      int tg = t0 + (r & 3) + 8 * (r >> 2) + 4 * hi;
      float v = s[r] * sf;
      p[r] = (tg >= srow) ? -3.0e38f : v;
    }
    float t8[8], t4[4];
    #pragma unroll
    for (int i = 0; i < 8; ++i) t8[i] = fmaxf(p[2 * i], p[2 * i + 1]);
    #pragma unroll
    for (int i = 0; i < 4; ++i) t4[i] = fmaxf(t8[2 * i], t8[2 * i + 1]);
    float mt = fmaxf(fmaxf(t4[0], t4[1]), fmaxf(t4[2], t4[3]));
    mt = fmaxf(mt, __shfl_xor(mt, 32));
    float mn = fmaxf(m, mt);
    float fac = __expf(m - mn);
    m = mn;
    l *= fac;
    #pragma unroll
    for (int r = 0; r < 16; ++r) p[r] = __expf(p[r] - mn);
    float s8[8], s4[4];
    #pragma unroll
    for (int i = 0; i < 8; ++i) s8[i] = p[2 * i] + p[2 * i + 1];
    #pragma unroll
    for (int i = 0; i < 4; ++i) s4[i] = s8[2 * i] + s8[2 * i + 1];
    float ps = (s4[0] + s4[1]) + (s4[2] + s4[3]);
    ps += __shfl_xor(ps, 32);
    l += ps;
    #pragma unroll
    for (int i = 0; i < 16; ++i) { o0[i] *= fac; o1[i] *= fac; }
    #pragma unroll
    for (int c = 0; c < 2; ++c) {
      unsigned X0 = pkbf(p[8 * c + 0], p[8 * c + 1]);
      unsigned X1 = pkbf(p[8 * c + 2], p[8 * c + 3]);
      unsigned Y0 = pkbf(p[8 * c + 4], p[8 * c + 5]);
      unsigned Y1 = pkbf(p[8 * c + 6], p[8 * c + 7]);
      unsigned z0 = hi ? X0 : Y0, z1 = hi ? X1 : Y1;
      unsigned r0 = __shfl_xor(z0, 32), r1 = __shfl_xor(z1, 32);
      union { unsigned u[4]; short8 v; } pb;
      pb.u[0] = hi ? r0 : X0;
      pb.u[1] = hi ? r1 : X1;
      pb.u[2] = hi ? Y0 : r0;
      pb.u[3] = hi ? Y1 : r1;
      o0 = __builtin_amdgcn_mfma_f32_32x32x16_bf16(vb0[c], pb.v, o0, 0, 0, 0);
      o1 = __builtin_amdgcn_mfma_f32_32x32x16_bf16(vb1[c], pb.v, o1, 0, 0, 0);
    }
  };

  for (int ti = 0; ti < nb; ++ti) {
    const int t0 = ti * 32;
    short8 kb[4];
    #pragma unroll
    for (int f = 0; f < 4; ++f) {
      int tw = t0 + lq;
      kb[f] = *(const short8*)(lds + tw * 128 + ((((f << 1) + hi) ^ (tw & 7)) << 4));
    }
    short8 vb0[2], vb1[2];
    #pragma unroll
    for (int c = 0; c < 2; ++c) {
      int ck = 4 * ti + 2 * c + hi;
      int d0 = lq;
      vb0[c] = *(const short8*)(lds + 65536 + d0 * 1024 + ((ck ^ (d0 & 15)) << 4));
      int d1 = 32 + lq;
      vb1[c] = *(const short8*)(lds + 65536 + d1 * 1024 + ((ck ^ (d1 & 15)) << 4));
    }
    if (ti < na) process(oa0, oa1, ma, la, qa_, sa, sfa, kb, vb0, vb1, t0);
    process(ob0, ob1, mb, lb, qb_, sb, sfb, kb, vb0, vb1, t0);
  }

  auto writeO = [&](const f32x16& o0, const f32x16& o1, float l, int srow) {
    float inv = (srow == 0) ? 0.0f : 1.0f / l;
    char* base = (char*)ctx + (((size_t)(b * S_ + srow)) * D_ + h * DK_) * 2;
    #pragma unroll
    for (int gg = 0; gg < 4; ++gg) {
      uint2 w0, w1;
      w0.x = pkbf(o0[4 * gg + 0] * inv, o0[4 * gg + 1] * inv);
      w0.y = pkbf(o0[4 * gg + 2] * inv, o0[4 * gg + 3] * inv);
      *(uint2*)(base + (8 * gg + 4 * hi) * 2) = w0;
      w1.x = pkbf(o1[4 * gg + 0] * inv, o1[4 * gg + 1] * inv);
      w1.y = pkbf(o1[4 * gg + 2] * inv, o1[4 * gg + 3] * inv);
      *(uint2*)(base + (32 + 8 * gg + 4 * hi) * 2) = w1;
    }
  };
  writeO(oa0, oa1, la, sa);
  writeO(ob0, ob1, lb, sb);
}

// ---------------- fused residual + LayerNorm (bf16 streams) ------------------
// v = xres + add (+ add2) in f32; LN; output bf16 x' (in-place safe) or, for
// FINAL, f32 to the output buffer. All loads/stores 16B coalesced.
template<int NADD, int FINAL>
__global__ __launch_bounds__(256) void ln_kernel(
    const uint4* __restrict__ xres, const uint4* __restrict__ add,
    const uint4* __restrict__ add2,
    const float* __restrict__ g, const float* __restrict__ bta,
    uint4* __restrict__ xb_out, float4* __restrict__ xf_out)
{
  const int lane = threadIdx.x & 63, wv = threadIdx.x >> 6;
  const size_t row = (size_t)blockIdx.x * 4 + wv;

  uint4 xr = xres[row * 64 + lane];
  uint4 ab = add[row * 64 + lane];
  const unsigned short* xp = (const unsigned short*)&xr;
  const unsigned short* ap = (const unsigned short*)&ab;
  float v[8];
  #pragma unroll
  for (int i = 0; i < 8; ++i) v[i] = b2f(xp[i]) + b2f(ap[i]);
  if (NADD == 2) {
    uint4 ab2 = add2[row * 64 + lane];
    const unsigned short* ap2 = (const unsigned short*)&ab2;
    #pragma unroll
    for (int i = 0; i < 8; ++i) v[i] += b2f(ap2[i]);
  }
  float s = 0.0f;
  #pragma unroll
  for (int i = 0; i < 8; ++i) s += v[i];
  s = waveReduceSum(s);
  float mu = s * (1.0f / 512.0f);
  float vs = 0.0f;
  #pragma unroll
  for (int i = 0; i < 8; ++i) { float dd = v[i] - mu; vs += dd * dd; }
  vs = waveReduceSum(vs);
  float rstd = rsqrtf(vs * (1.0f / 512.0f) + 1e-5f);

  const int c0i = lane * 8;
  float4 gg0 = *(const float4*)(g + c0i), gg1 = *(const float4*)(g + c0i + 4);
  float4 bb0 = *(const float4*)(bta + c0i), bb1 = *(const float4*)(bta + c0i + 4);
  float o[8];
  o[0] = (v[0] - mu) * rstd * gg0.x + bb0.x;
  o[1] = (v[1] - mu) * rstd * gg0.y + bb0.y;
  o[2] = (v[2] - mu) * rstd * gg0.z + bb0.z;
  o[3] = (v[3] - mu) * rstd * gg0.w + bb0.w;
  o[4] = (v[4] - mu) * rstd * gg1.x + bb1.x;
  o[5] = (v[5] - mu) * rstd * gg1.y + bb1.y;
  o[6] = (v[6] - mu) * rstd * gg1.z + bb1.z;
  o[7] = (v[7] - mu) * rstd * gg1.w + bb1.w;

  if (FINAL) {
    float4 w0, w1;
    w0.x = o[0]; w0.y = o[1]; w0.z = o[2]; w0.w = o[3];
    w1.x = o[4]; w1.y = o[5]; w1.z = o[6]; w1.w = o[7];
    xf_out[row * 128 + lane * 2] = w0;
    xf_out[row * 128 + lane * 2 + 1] = w1;
  } else {
    uint4 pw;
    pw.x = pkbf(o[0], o[1]);
    pw.y = pkbf(o[2], o[3]);
    pw.z = pkbf(o[4], o[5]);
    pw.w = pkbf(o[6], o[7]);
    xb_out[row * 64 + lane] = pw;
  }
}

// ---------------- launcher ---------------------------------------------------
extern "C" void kernel_launch(void* const* d_in, const int* in_sizes, int n_in,
                              void* d_out, int out_size, void* d_ws, size_t ws_size,
                              hipStream_t stream) {
  (void)in_sizes; (void)n_in; (void)out_size; (void)ws_size;
  const float* q   = (const float*)d_in[0];
  const float* qa  = (const float*)d_in[1];
  const float* frr = (const float*)d_in[2];
  const float* pos = (const float*)d_in[3];
  const float* Wk  = (const float*)d_in[4];
  const float* bk  = (const float*)d_in[5];
  const float* Wv  = (const float*)d_in[6];
  const float* bv  = (const float*)d_in[7];
  const float* Wo  = (const float*)d_in[8];
  const float* bo  = (const float*)d_in[9];
  const float* W1  = (const float*)d_in[10];
  const float* b1  = (const float*)d_in[11];
  const float* W2  = (const float*)d_in[12];
  const float* b2  = (const float*)d_in[13];
  const float* g1  = (const float*)d_in[14];
  const float* be1 = (const float*)d_in[15];
  const float* g2  = (const float*)d_in[16];
  const float* be2 = (const float*)d_in[17];

  char* ws = (char*)d_ws;
  __hip_bfloat16* xb   = (__hip_bfloat16*)(ws + 33554432);
  __hip_bfloat16* yb   = (__hip_bfloat16*)(ws + 50331648);
  __hip_bfloat16* kqb  = (__hip_bfloat16*)(ws + 67108864);
  __hip_bfloat16* vtb  = (__hip_bfloat16*)(ws + 83886080);
  __hip_bfloat16* ctxb = (__hip_bfloat16*)(ws + 100663296);
  __hip_bfloat16* hb   = (__hip_bfloat16*)(ws + 117440512);     // 67.1 MB
  __hip_bfloat16* wkb  = (__hip_bfloat16*)(ws + 184549376);
  __hip_bfloat16* wvb  = (__hip_bfloat16*)(ws + 186646528);
  __hip_bfloat16* wob  = (__hip_bfloat16*)(ws + 188743680);
  __hip_bfloat16* w1b  = (__hip_bfloat16*)(ws + 190840832);
  __hip_bfloat16* w2b  = (__hip_bfloat16*)(ws + 199229440);
  // dead-region reuse (per-layer lifetimes):
  __hip_bfloat16* obf = (__hip_bfloat16*)(ws + 67108864);   // over kqb (dead post-fattn)
  __hip_bfloat16* pf0 = (__hip_bfloat16*)(ws + 83886080);   // over vtb (dead post-fattn)

  prep_kernel<<<8192, 256, 0, stream>>>((const float4*)q, (const float4*)qa,
                                        (const float4*)pos, (uint2*)xb, (uint2*)yb);
  cast_kernel<<<1024, 256, 0, stream>>>((const float4*)Wk, (uint2*)wkb, 262144);
  cast_kernel<<<1024, 256, 0, stream>>>((const float4*)Wv, (uint2*)wvb, 262144);
  cast_kernel<<<1024, 256, 0, stream>>>((const float4*)Wo, (uint2*)wob, 262144);
  cast_kernel<<<4096, 256, 0, stream>>>((const float4*)W1, (uint2*)w1b, 1048576);
  cast_kernel<<<4096, 256, 0, stream>>>((const float4*)W2, (uint2*)w2b, 1048576);

  for (int l = 0; l < L_; ++l) {
    // fused K-proj (z=0, row-major) + V-proj (z=1, vT transposed)
    gemm128_kernel<0,3><<<dim3(4, 128, 2), 256, 0, stream>>>(
        xb, wkb + (size_t)l * 262144, bk + l * 512,
        yb, wvb + (size_t)l * 262144, bv + l * 512,
        kqb, vtb, 512, 512, 512);
    fattn_kernel<<<256, 512, 0, stream>>>(kqb, vtb, frr, ctxb);
    gemm128_kernel<0,0><<<dim3(4, 128, 1), 256, 0, stream>>>(
        ctxb, wob + (size_t)l * 262144, bo + l * 512,
        nullptr, nullptr, nullptr, obf, nullptr, 512, 512, 512);
    // residual + LN1 (bf16 in-place)
    ln_kernel<1,0><<<4096, 256, 0, stream>>>(
        (const uint4*)xb, (const uint4*)obf, nullptr,
        g1 + l * 512, be1 + l * 512, (uint4*)xb, nullptr);
    // FFN1 (ReLU)
    gemm128_kernel<1,0><<<dim3(16, 128, 1), 256, 0, stream>>>(
        xb, w1b + (size_t)l * 1048576, b1 + l * 2048,
        nullptr, nullptr, nullptr, hb, nullptr, 2048, 512, 512);
    // FFN2 (unsplit, K=2048)
    gemm128_kernel<0,0><<<dim3(4, 128, 1), 256, 0, stream>>>(
        hb, w2b + (size_t)l * 1048576, b2 + l * 512,
        nullptr, nullptr, nullptr, pf0, nullptr, 512, 2048, 2048);
    // residual + LN2 (bf16 in-place; last layer writes f32 d_out)
    if (l == L_ - 1) {
      ln_kernel<1,1><<<4096, 256, 0, stream>>>(
          (const uint4*)xb, (const uint4*)pf0, nullptr,
          g2 + l * 512, be2 + l * 512, nullptr, (float4*)d_out);
    } else {
      ln_kernel<1,0><<<4096, 256, 0, stream>>>(
          (const uint4*)xb, (const uint4*)pf0, nullptr,
          g2 + l * 512, be2 + l * 512, (uint4*)xb, nullptr);
    }
  }
}

// Round 16
// 733.660 us; speedup vs baseline: 1.0293x; 1.0293x over previous
//
#include <hip/hip_runtime.h>
#include <hip/hip_bf16.h>

// Problem constants
constexpr int B_ = 32, S_ = 512, D_ = 512, H_ = 8, L_ = 4, F_ = 2048, DK_ = 64;

typedef __attribute__((ext_vector_type(8))) short short8;
typedef __attribute__((ext_vector_type(4))) float f32x4;
typedef __attribute__((ext_vector_type(16))) float f32x16;

__device__ inline unsigned short f2b(float f) {
  union { __hip_bfloat16 h; unsigned short u; } cv;
  cv.h = __float2bfloat16(f);
  return cv.u;
}
__device__ inline float b2f(unsigned short u) {
  union { unsigned int i; float f; } c;
  c.i = ((unsigned int)u) << 16;
  return c.f;
}
__device__ inline unsigned pkbf(float a, float b) {
  unsigned r;
  asm("v_cvt_pk_bf16_f32 %0, %1, %2" : "=v"(r) : "v"(a), "v"(b));
  return r;
}
__device__ inline float waveReduceSum(float v) {
  #pragma unroll
  for (int o = 32; o > 0; o >>= 1) v += __shfl_xor(v, o);
  return v;
}

// ---------------- prep: xb = bf16(q + pos), yb = bf16(qa + pos) --------------
__global__ void prep_kernel(const float4* __restrict__ q, const float4* __restrict__ qa,
                            const float4* __restrict__ pos,
                            uint2* __restrict__ xb, uint2* __restrict__ yb) {
  int i = blockIdx.x * blockDim.x + threadIdx.x;  // 2,097,152 exact
  float4 p = pos[i & 65535];
  float4 a = q[i], c = qa[i];
  uint2 px, py;
  px.x = pkbf(a.x + p.x, a.y + p.y);
  px.y = pkbf(a.z + p.z, a.w + p.w);
  py.x = pkbf(c.x + p.x, c.y + p.y);
  py.y = pkbf(c.z + p.z, c.w + p.w);
  xb[i] = px;
  yb[i] = py;
}

// ---------------- cast fp32 -> bf16 ------------------------------------------
__global__ void cast_kernel(const float4* __restrict__ src, uint2* __restrict__ dst, int n4) {
  int i = blockIdx.x * blockDim.x + threadIdx.x;
  if (i >= n4) return;
  float4 v = src[i];
  uint2 p;
  p.x = pkbf(v.x, v.y);
  p.y = pkbf(v.z, v.w);
  dst[i] = p;
}

// ---------------- 128x128 MFMA GEMM, 2-phase dbuf, 32KB LDS ------------------
// STORE 0: bf16 row-major (z picks Cb/Cb2, bias only z==0).
// STORE 3: dual-GEMM — z==0: A/W/bias -> Cb row-major;
//                      z==1: A2/W2/bias2 -> Cb2 vT[((b*8+h)*64+d)*512+t].
template<int RELU, int STORE>
__global__ __launch_bounds__(256, 2) void gemm128_kernel(
    const __hip_bfloat16* __restrict__ A,
    const __hip_bfloat16* __restrict__ W,
    const float* __restrict__ bias,
    const __hip_bfloat16* __restrict__ A2,
    const __hip_bfloat16* __restrict__ W2,
    const float* __restrict__ bias2,
    __hip_bfloat16* __restrict__ Cb,
    __hip_bfloat16* __restrict__ Cb2,
    int Ndim, int Kdim, int kLen)
{
  __shared__ char lds[32768];  // A: buf*8192, W: 16384 + buf*8192
  const int tid = threadIdx.x, wave = tid >> 6, lane = tid & 63;
  const int rl = lane & 15, gq = lane >> 4;
  const int wr = wave >> 1, wc = wave & 1;

  const int nwg = gridDim.x * gridDim.y;
  const int lin = blockIdx.y * gridDim.x + blockIdx.x;
  const int swz = (lin & 7) * (nwg >> 3) + (lin >> 3);
  const int bx = swz % gridDim.x, by = swz / gridDim.x;

  const int row0 = by * 128;
  const int col0 = bx * 128;

  const __hip_bfloat16* Ap = A;
  const __hip_bfloat16* Wp = W;
  const float* bp = bias;
  int kOff = blockIdx.z * kLen;
  if (STORE == 3) {
    kOff = 0;
    if (blockIdx.z) { Ap = A2; Wp = W2; bp = bias2; }
  }

  f32x4 acc[4][4] = {};
  const int ntiles = kLen >> 5;

  auto stage = [&](int kt, int d) {
    const int kbase = kOff + (kt << 5);
    #pragma unroll
    for (int r = 0; r < 2; ++r) {
      int p = r * 4096 + tid * 16;
      int R = p >> 6, c = (p >> 4) & 3;
      int gc = c ^ ((R >> 1) & 3);
      const __hip_bfloat16* srcA = Ap + (size_t)(row0 + R) * Kdim + kbase + gc * 8;
      __builtin_amdgcn_global_load_lds(
          (const __attribute__((address_space(1))) void*)srcA,
          (__attribute__((address_space(3))) void*)(lds + d * 8192 + p), 16, 0, 0);
      const __hip_bfloat16* srcW = Wp + (size_t)(col0 + R) * Kdim + kbase + gc * 8;
      __builtin_amdgcn_global_load_lds(
          (const __attribute__((address_space(1))) void*)srcW,
          (__attribute__((address_space(3))) void*)(lds + 16384 + d * 8192 + p), 16, 0, 0);
    }
  };

  stage(0, 0);
  __syncthreads();  // tile 0 resident
  for (int kt = 0; kt < ntiles; ++kt) {
    const int d = kt & 1;
    if (kt + 1 < ntiles) stage(kt + 1, d ^ 1);  // issue early, fly under MFMA

    short8 aF[4], bF[4];
    #pragma unroll
    for (int m = 0; m < 4; ++m) {
      int rr = wr * 64 + m * 16 + rl;
      aF[m] = *(const short8*)(lds + d * 8192 + rr * 64 + ((gq ^ ((rr >> 1) & 3)) << 4));
    }
    #pragma unroll
    for (int n = 0; n < 4; ++n) {
      int rr = wc * 64 + n * 16 + rl;
      bF[n] = *(const short8*)(lds + 16384 + d * 8192 + rr * 64 + ((gq ^ ((rr >> 1) & 3)) << 4));
    }
    __builtin_amdgcn_s_setprio(1);
    #pragma unroll
    for (int m = 0; m < 4; ++m)
      #pragma unroll
      for (int n = 0; n < 4; ++n)
        acc[m][n] = __builtin_amdgcn_mfma_f32_16x16x32_bf16(aF[m], bF[n], acc[m][n], 0, 0, 0);
    __builtin_amdgcn_s_setprio(0);
    __syncthreads();  // next tile landed + all reads of buf d done
  }

  // ---------------- coalesced epilogue (LDS re-layout) ----------------
  char* sw = lds + wave * 8192;  // per-wave 64 rows * 128B scratch
  const bool vt = (STORE == 3) && (blockIdx.z == 1);
  const bool addb = (STORE == 3) ? true : ((bias != nullptr) && (blockIdx.z == 0));
  float bvv[4];
  #pragma unroll
  for (int n = 0; n < 4; ++n)
    bvv[n] = addb ? bp[col0 + wc * 64 + n * 16 + rl] : 0.0f;

  #pragma unroll
  for (int n = 0; n < 4; ++n)
    #pragma unroll
    for (int m = 0; m < 4; ++m)
      #pragma unroll
      for (int j = 0; j < 4; ++j) {
        float val = acc[m][n][j] + bvv[n];
        if (RELU) val = fmaxf(val, 0.0f);
        int addr;
        if (vt) {
          int orow = n * 16 + rl, ocol = m * 16 + gq * 4 + j;
          addr = orow * 128 + ((ocol * 2) ^ ((orow & 7) << 4));
        } else {
          int orow = m * 16 + gq * 4 + j;
          addr = orow * 128 + (((n * 16 + rl) * 2) ^ (((orow >> 1) & 7) << 4));
        }
        *(unsigned short*)(sw + addr) = f2b(val);
      }
  asm volatile("s_waitcnt lgkmcnt(0)" ::: "memory");
  __builtin_amdgcn_sched_barrier(0);

  __hip_bfloat16* Cbd = blockIdx.z ? Cb2 : Cb;
  const int cchunk = lane & 7;
  if (vt) {
    const int bh64 = ((row0 >> 9) * 8 + (col0 >> 6) + wc) * 64;
    const int tbase = (row0 & 511) + wr * 64;
    #pragma unroll
    for (int it = 0; it < 8; ++it) {
      int d0 = it * 8 + (lane >> 3);
      uint4 vv = *(const uint4*)(sw + d0 * 128 + ((cchunk * 16) ^ ((d0 & 7) << 4)));
      *(uint4*)((char*)Cbd + ((size_t)(bh64 + d0) * 512 + tbase) * 2 + cchunk * 16) = vv;
    }
  } else {
    #pragma unroll
    for (int it = 0; it < 8; ++it) {
      int orow = it * 8 + (lane >> 3);
      uint4 vv = *(const uint4*)(sw + orow * 128 + ((cchunk * 16) ^ (((orow >> 1) & 7) << 4)));
      *(uint4*)((char*)Cbd + ((size_t)(row0 + wr * 64 + orow) * Ndim + col0 + wc * 64) * 2 +
                cchunk * 16) = vv;
    }
  }
}

// ---------------- flash attention: swapped-QK^T, in-register softmax ---------
// grid 256 = (b,h), 512 thr. Block stages K[512][64] + vT[64][512] once
// (128KB LDS, chunk-XOR swizzles), then 8 waves run barrier-free. Wave w owns
// q-tiles {w, 15-w}; swapped 32x32x16 MFMAs put q on the output COLUMN so
// softmax state is lane-scalar; P repacked in-register into PV's B-operand.
__global__ __launch_bounds__(512, 2) void fattn_kernel(
    const __hip_bfloat16* __restrict__ kq,  // [B*S, D]
    const __hip_bfloat16* __restrict__ vT,  // [(b*8+h)*64+d][t]
    const float* __restrict__ fr,           // [B*S]
    __hip_bfloat16* __restrict__ ctx)       // [B*S, D]
{
  __shared__ char lds[131072];  // K [0,64K) ck^(r&7); vT [64K,128K) ck^(d&15)
  const int tid = threadIdx.x, wave = tid >> 6, lane = tid & 63;
  const int lq = lane & 31, hi = lane >> 5;
  const int bh = blockIdx.x;
  const int b = bh >> 3, h = bh & 7;
  const size_t kqbase = ((size_t)b * S_) * D_ + h * DK_;
  const size_t vtbase = ((size_t)bh * DK_) * S_;
  const char* kg = (const char*)kq + kqbase * 2;
  const char* vg = (const char*)vT + vtbase * 2;

  #pragma unroll
  for (int i = 0; i < 8; ++i) {
    int p = i * 8192 + tid * 16;
    int r = p >> 7, ck = (p >> 4) & 7;
    __builtin_amdgcn_global_load_lds(
        (const __attribute__((address_space(1))) void*)(kg + (size_t)r * 1024 + ((ck ^ (r & 7)) << 4)),
        (__attribute__((address_space(3))) void*)(lds + p), 16, 0, 0);
  }
  #pragma unroll
  for (int i = 0; i < 8; ++i) {
    int p = i * 8192 + tid * 16;
    int d = p >> 10, ck = (p >> 4) & 63;
    __builtin_amdgcn_global_load_lds(
        (const __attribute__((address_space(1))) void*)(vg + (size_t)d * 1024 + ((ck ^ (d & 15)) << 4)),
        (__attribute__((address_space(3))) void*)(lds + 65536 + p), 16, 0, 0);
  }

  const int qia = wave, qib = 15 - wave;
  const int na = qia + 1, nb = qib + 1;
  const int sa = qia * 32 + lq, sb = qib * 32 + lq;
  const float sfa = fr[b * S_ + sa] * 0.125f;
  const float sfb = fr[b * S_ + sb] * 0.125f;

  asm volatile("s_waitcnt vmcnt(0)" ::: "memory");
  __builtin_amdgcn_sched_barrier(0);
  __builtin_amdgcn_s_barrier();

  short8 qa_[4], qb_[4];
  #pragma unroll
  for (int f = 0; f < 4; ++f) {
    qa_[f] = *(const short8*)(lds + sa * 128 + ((((f << 1) + hi) ^ (sa & 7)) << 4));
    qb_[f] = *(const short8*)(lds + sb * 128 + ((((f << 1) + hi) ^ (sb & 7)) << 4));
  }

  f32x16 oa0 = {}, oa1 = {}, ob0 = {}, ob1 = {};
  float ma = -3.0e38f, la = 0.0f, mb = -3.0e38f, lb = 0.0f;

  auto process = [&](f32x16& o0, f32x16& o1, float& m, float& l,
                     const short8* qf, int srow, float sf,
                     const short8* kb, const short8* vb0, const short8* vb1,
                     int t0) {
    f32x16 s = {};
    #pragma unroll
    for (int f = 0; f < 4; ++f)
      s = __builtin_amdgcn_mfma_f32_32x32x16_bf16(kb[f], qf[f], s, 0, 0, 0);
    float p[16];
    #pragma unroll
    for (int r = 0; r < 16; ++r) {
      int tg = t0 + (r & 3) + 8 * (r >> 2) + 4 * hi;
      float v = s[r] * sf;
      p[r] = (tg >= srow) ? -3.0e38f : v;
    }
    float t8[8], t4[4];
    #pragma unroll
    for (int i = 0; i < 8; ++i) t8[i] = fmaxf(p[2 * i], p[2 * i + 1]);
    #pragma unroll
    for (int i = 0; i < 4; ++i) t4[i] = fmaxf(t8[2 * i], t8[2 * i + 1]);
    float mt = fmaxf(fmaxf(t4[0], t4[1]), fmaxf(t4[2], t4[3]));
    mt = fmaxf(mt, __shfl_xor(mt, 32));
    float mn = fmaxf(m, mt);
    float fac = __expf(m - mn);
    m = mn;
    l *= fac;
    #pragma unroll
    for (int r = 0; r < 16; ++r) p[r] = __expf(p[r] - mn);
    float s8[8], s4[4];
    #pragma unroll
    for (int i = 0; i < 8; ++i) s8[i] = p[2 * i] + p[2 * i + 1];
    #pragma unroll
    for (int i = 0; i < 4; ++i) s4[i] = s8[2 * i] + s8[2 * i + 1];
    float ps = (s4[0] + s4[1]) + (s4[2] + s4[3]);
    ps += __shfl_xor(ps, 32);
    l += ps;
    #pragma unroll
    for (int i = 0; i < 16; ++i) { o0[i] *= fac; o1[i] *= fac; }
    #pragma unroll
    for (int c = 0; c < 2; ++c) {
      unsigned X0 = pkbf(p[8 * c + 0], p[8 * c + 1]);
      unsigned X1 = pkbf(p[8 * c + 2], p[8 * c + 3]);
      unsigned Y0 = pkbf(p[8 * c + 4], p[8 * c + 5]);
      unsigned Y1 = pkbf(p[8 * c + 6], p[8 * c + 7]);
      unsigned z0 = hi ? X0 : Y0, z1 = hi ? X1 : Y1;
      unsigned r0 = __shfl_xor(z0, 32), r1 = __shfl_xor(z1, 32);
      union { unsigned u[4]; short8 v; } pb;
      pb.u[0] = hi ? r0 : X0;
      pb.u[1] = hi ? r1 : X1;
      pb.u[2] = hi ? Y0 : r0;
      pb.u[3] = hi ? Y1 : r1;
      o0 = __builtin_amdgcn_mfma_f32_32x32x16_bf16(vb0[c], pb.v, o0, 0, 0, 0);
      o1 = __builtin_amdgcn_mfma_f32_32x32x16_bf16(vb1[c], pb.v, o1, 0, 0, 0);
    }
  };

  for (int ti = 0; ti < nb; ++ti) {
    const int t0 = ti * 32;
    short8 kb[4];
    #pragma unroll
    for (int f = 0; f < 4; ++f) {
      int tw = t0 + lq;
      kb[f] = *(const short8*)(lds + tw * 128 + ((((f << 1) + hi) ^ (tw & 7)) << 4));
    }
    short8 vb0[2], vb1[2];
    #pragma unroll
    for (int c = 0; c < 2; ++c) {
      int ck = 4 * ti + 2 * c + hi;
      int d0 = lq;
      vb0[c] = *(const short8*)(lds + 65536 + d0 * 1024 + ((ck ^ (d0 & 15)) << 4));
      int d1 = 32 + lq;
      vb1[c] = *(const short8*)(lds + 65536 + d1 * 1024 + ((ck ^ (d1 & 15)) << 4));
    }
    if (ti < na) process(oa0, oa1, ma, la, qa_, sa, sfa, kb, vb0, vb1, t0);
    process(ob0, ob1, mb, lb, qb_, sb, sfb, kb, vb0, vb1, t0);
  }

  auto writeO = [&](const f32x16& o0, const f32x16& o1, float l, int srow) {
    float inv = (srow == 0) ? 0.0f : 1.0f / l;
    char* base = (char*)ctx + (((size_t)(b * S_ + srow)) * D_ + h * DK_) * 2;
    #pragma unroll
    for (int gg = 0; gg < 4; ++gg) {
      uint2 w0, w1;
      w0.x = pkbf(o0[4 * gg + 0] * inv, o0[4 * gg + 1] * inv);
      w0.y = pkbf(o0[4 * gg + 2] * inv, o0[4 * gg + 3] * inv);
      *(uint2*)(base + (8 * gg + 4 * hi) * 2) = w0;
      w1.x = pkbf(o1[4 * gg + 0] * inv, o1[4 * gg + 1] * inv);
      w1.y = pkbf(o1[4 * gg + 2] * inv, o1[4 * gg + 3] * inv);
      *(uint2*)(base + (32 + 8 * gg + 4 * hi) * 2) = w1;
    }
  };
  writeO(oa0, oa1, la, sa);
  writeO(ob0, ob1, lb, sb);
}

// ---------------- fused residual + LayerNorm (bf16 streams) ------------------
// v = xres + add (+ add2) in f32; LN; output bf16 x' (in-place safe) or, for
// FINAL, f32 to the output buffer. All loads/stores 16B coalesced.
template<int NADD, int FINAL>
__global__ __launch_bounds__(256) void ln_kernel(
    const uint4* __restrict__ xres, const uint4* __restrict__ add,
    const uint4* __restrict__ add2,
    const float* __restrict__ g, const float* __restrict__ bta,
    uint4* __restrict__ xb_out, float4* __restrict__ xf_out)
{
  const int lane = threadIdx.x & 63, wv = threadIdx.x >> 6;
  const size_t row = (size_t)blockIdx.x * 4 + wv;

  uint4 xr = xres[row * 64 + lane];
  uint4 ab = add[row * 64 + lane];
  const unsigned short* xp = (const unsigned short*)&xr;
  const unsigned short* ap = (const unsigned short*)&ab;
  float v[8];
  #pragma unroll
  for (int i = 0; i < 8; ++i) v[i] = b2f(xp[i]) + b2f(ap[i]);
  if (NADD == 2) {
    uint4 ab2 = add2[row * 64 + lane];
    const unsigned short* ap2 = (const unsigned short*)&ab2;
    #pragma unroll
    for (int i = 0; i < 8; ++i) v[i] += b2f(ap2[i]);
  }
  float s = 0.0f;
  #pragma unroll
  for (int i = 0; i < 8; ++i) s += v[i];
  s = waveReduceSum(s);
  float mu = s * (1.0f / 512.0f);
  float vs = 0.0f;
  #pragma unroll
  for (int i = 0; i < 8; ++i) { float dd = v[i] - mu; vs += dd * dd; }
  vs = waveReduceSum(vs);
  float rstd = rsqrtf(vs * (1.0f / 512.0f) + 1e-5f);

  const int c0i = lane * 8;
  float4 gg0 = *(const float4*)(g + c0i), gg1 = *(const float4*)(g + c0i + 4);
  float4 bb0 = *(const float4*)(bta + c0i), bb1 = *(const float4*)(bta + c0i + 4);
  float o[8];
  o[0] = (v[0] - mu) * rstd * gg0.x + bb0.x;
  o[1] = (v[1] - mu) * rstd * gg0.y + bb0.y;
  o[2] = (v[2] - mu) * rstd * gg0.z + bb0.z;
  o[3] = (v[3] - mu) * rstd * gg0.w + bb0.w;
  o[4] = (v[4] - mu) * rstd * gg1.x + bb1.x;
  o[5] = (v[5] - mu) * rstd * gg1.y + bb1.y;
  o[6] = (v[6] - mu) * rstd * gg1.z + bb1.z;
  o[7] = (v[7] - mu) * rstd * gg1.w + bb1.w;

  if (FINAL) {
    float4 w0, w1;
    w0.x = o[0]; w0.y = o[1]; w0.z = o[2]; w0.w = o[3];
    w1.x = o[4]; w1.y = o[5]; w1.z = o[6]; w1.w = o[7];
    xf_out[row * 128 + lane * 2] = w0;
    xf_out[row * 128 + lane * 2 + 1] = w1;
  } else {
    uint4 pw;
    pw.x = pkbf(o[0], o[1]);
    pw.y = pkbf(o[2], o[3]);
    pw.z = pkbf(o[4], o[5]);
    pw.w = pkbf(o[6], o[7]);
    xb_out[row * 64 + lane] = pw;
  }
}

// ---------------- launcher ---------------------------------------------------
extern "C" void kernel_launch(void* const* d_in, const int* in_sizes, int n_in,
                              void* d_out, int out_size, void* d_ws, size_t ws_size,
                              hipStream_t stream) {
  (void)in_sizes; (void)n_in; (void)out_size; (void)ws_size;
  const float* q   = (const float*)d_in[0];
  const float* qa  = (const float*)d_in[1];
  const float* frr = (const float*)d_in[2];
  const float* pos = (const float*)d_in[3];
  const float* Wk  = (const float*)d_in[4];
  const float* bk  = (const float*)d_in[5];
  const float* Wv  = (const float*)d_in[6];
  const float* bv  = (const float*)d_in[7];
  const float* Wo  = (const float*)d_in[8];
  const float* bo  = (const float*)d_in[9];
  const float* W1  = (const float*)d_in[10];
  const float* b1  = (const float*)d_in[11];
  const float* W2  = (const float*)d_in[12];
  const float* b2  = (const float*)d_in[13];
  const float* g1  = (const float*)d_in[14];
  const float* be1 = (const float*)d_in[15];
  const float* g2  = (const float*)d_in[16];
  const float* be2 = (const float*)d_in[17];

  char* ws = (char*)d_ws;
  __hip_bfloat16* xb   = (__hip_bfloat16*)(ws + 33554432);
  __hip_bfloat16* yb   = (__hip_bfloat16*)(ws + 50331648);
  __hip_bfloat16* kqb  = (__hip_bfloat16*)(ws + 67108864);
  __hip_bfloat16* vtb  = (__hip_bfloat16*)(ws + 83886080);
  __hip_bfloat16* ctxb = (__hip_bfloat16*)(ws + 100663296);
  __hip_bfloat16* hb   = (__hip_bfloat16*)(ws + 117440512);     // 67.1 MB
  __hip_bfloat16* wkb  = (__hip_bfloat16*)(ws + 184549376);
  __hip_bfloat16* wvb  = (__hip_bfloat16*)(ws + 186646528);
  __hip_bfloat16* wob  = (__hip_bfloat16*)(ws + 188743680);
  __hip_bfloat16* w1b  = (__hip_bfloat16*)(ws + 190840832);
  __hip_bfloat16* w2b  = (__hip_bfloat16*)(ws + 199229440);
  // dead-region reuse (per-layer lifetimes):
  __hip_bfloat16* obf = (__hip_bfloat16*)(ws + 67108864);   // over kqb (dead post-fattn)
  __hip_bfloat16* pf0 = (__hip_bfloat16*)(ws + 83886080);   // over vtb (dead post-fattn)
  __hip_bfloat16* pf1 = (__hip_bfloat16*)(ws + 100663296);  // over ctxb (dead post-projO)

  prep_kernel<<<8192, 256, 0, stream>>>((const float4*)q, (const float4*)qa,
                                        (const float4*)pos, (uint2*)xb, (uint2*)yb);
  cast_kernel<<<1024, 256, 0, stream>>>((const float4*)Wk, (uint2*)wkb, 262144);
  cast_kernel<<<1024, 256, 0, stream>>>((const float4*)Wv, (uint2*)wvb, 262144);
  cast_kernel<<<1024, 256, 0, stream>>>((const float4*)Wo, (uint2*)wob, 262144);
  cast_kernel<<<4096, 256, 0, stream>>>((const float4*)W1, (uint2*)w1b, 1048576);
  cast_kernel<<<4096, 256, 0, stream>>>((const float4*)W2, (uint2*)w2b, 1048576);

  for (int l = 0; l < L_; ++l) {
    // fused K-proj (z=0, row-major) + V-proj (z=1, vT transposed)
    gemm128_kernel<0,3><<<dim3(4, 128, 2), 256, 0, stream>>>(
        xb, wkb + (size_t)l * 262144, bk + l * 512,
        yb, wvb + (size_t)l * 262144, bv + l * 512,
        kqb, vtb, 512, 512, 512);
    fattn_kernel<<<256, 512, 0, stream>>>(kqb, vtb, frr, ctxb);
    gemm128_kernel<0,0><<<dim3(4, 128, 1), 256, 0, stream>>>(
        ctxb, wob + (size_t)l * 262144, bo + l * 512,
        nullptr, nullptr, nullptr, obf, nullptr, 512, 512, 512);
    // residual + LN1 (bf16 in-place)
    ln_kernel<1,0><<<4096, 256, 0, stream>>>(
        (const uint4*)xb, (const uint4*)obf, nullptr,
        g1 + l * 512, be1 + l * 512, (uint4*)xb, nullptr);
    // FFN1 (ReLU)
    gemm128_kernel<1,0><<<dim3(16, 128, 1), 256, 0, stream>>>(
        xb, w1b + (size_t)l * 1048576, b1 + l * 2048,
        nullptr, nullptr, nullptr, hb, nullptr, 2048, 512, 512);
    // FFN2 split-K=2
    gemm128_kernel<0,0><<<dim3(4, 128, 2), 256, 0, stream>>>(
        hb, w2b + (size_t)l * 1048576, b2 + l * 512,
        nullptr, nullptr, nullptr, pf0, pf1, 512, 2048, 1024);
    // residual + LN2 (bf16 in-place; last layer writes f32 d_out)
    if (l == L_ - 1) {
      ln_kernel<2,1><<<4096, 256, 0, stream>>>(
          (const uint4*)xb, (const uint4*)pf0, (const uint4*)pf1,
          g2 + l * 512, be2 + l * 512, nullptr, (float4*)d_out);
    } else {
      ln_kernel<2,0><<<4096, 256, 0, stream>>>(
          (const uint4*)xb, (const uint4*)pf0, (const uint4*)pf1,
          g2 + l * 512, be2 + l * 512, (uint4*)xb, nullptr);
    }
  }
}

// Round 17
// 722.367 us; speedup vs baseline: 1.0454x; 1.0156x over previous
//
#include <hip/hip_runtime.h>
#include <hip/hip_bf16.h>

// Problem constants
constexpr int B_ = 32, S_ = 512, D_ = 512, H_ = 8, L_ = 4, F_ = 2048, DK_ = 64;

typedef __attribute__((ext_vector_type(8))) short short8;
typedef __attribute__((ext_vector_type(4))) float f32x4;
typedef __attribute__((ext_vector_type(16))) float f32x16;

__device__ inline unsigned short f2b(float f) {
  union { __hip_bfloat16 h; unsigned short u; } cv;
  cv.h = __float2bfloat16(f);
  return cv.u;
}
__device__ inline float b2f(unsigned short u) {
  union { unsigned int i; float f; } c;
  c.i = ((unsigned int)u) << 16;
  return c.f;
}
__device__ inline unsigned pkbf(float a, float b) {
  unsigned r;
  asm("v_cvt_pk_bf16_f32 %0, %1, %2" : "=v"(r) : "v"(a), "v"(b));
  return r;
}
__device__ inline float waveReduceSum(float v) {
  #pragma unroll
  for (int o = 32; o > 0; o >>= 1) v += __shfl_xor(v, o);
  return v;
}

// ---------------- prep: xb = bf16(q + pos), yb = bf16(qa + pos) --------------
__global__ void prep_kernel(const float4* __restrict__ q, const float4* __restrict__ qa,
                            const float4* __restrict__ pos,
                            uint2* __restrict__ xb, uint2* __restrict__ yb) {
  int i = blockIdx.x * blockDim.x + threadIdx.x;  // 2,097,152 exact
  float4 p = pos[i & 65535];
  float4 a = q[i], c = qa[i];
  uint2 px, py;
  px.x = pkbf(a.x + p.x, a.y + p.y);
  px.y = pkbf(a.z + p.z, a.w + p.w);
  py.x = pkbf(c.x + p.x, c.y + p.y);
  py.y = pkbf(c.z + p.z, c.w + p.w);
  xb[i] = px;
  yb[i] = py;
}

// ---------------- fused cast of ALL weights (dst is contiguous) --------------
// segments (float4 idx): Wk [0,262144), Wv [262144,524288), Wo [524288,786432),
// W1 [786432,1835008), W2 [1835008,2883584). dst = wkb base (bf16, contiguous).
__global__ void cast_all_kernel(const float4* __restrict__ wk, const float4* __restrict__ wv,
                                const float4* __restrict__ wo, const float4* __restrict__ w1,
                                const float4* __restrict__ w2, uint2* __restrict__ dst) {
  int i = blockIdx.x * blockDim.x + threadIdx.x;  // 0..2883583 exact
  const float4* s;
  int off;
  if (i < 786432) {
    if (i < 262144) { s = wk; off = i; }
    else if (i < 524288) { s = wv; off = i - 262144; }
    else { s = wo; off = i - 524288; }
  } else if (i < 1835008) {
    s = w1; off = i - 786432;
  } else {
    s = w2; off = i - 1835008;
  }
  float4 v = s[off];
  uint2 p;
  p.x = pkbf(v.x, v.y);
  p.y = pkbf(v.z, v.w);
  dst[i] = p;
}

// ---------------- 128x128 MFMA GEMM, 2-phase dbuf, 32KB LDS ------------------
// STORE 0: bf16 row-major (z picks Cb/Cb2, bias only z==0).
// STORE 3: dual-GEMM — z==0: A/W/bias -> Cb row-major;
//                      z==1: A2/W2/bias2 -> Cb2 vT[((b*8+h)*64+d)*512+t].
template<int RELU, int STORE>
__global__ __launch_bounds__(256, 2) void gemm128_kernel(
    const __hip_bfloat16* __restrict__ A,
    const __hip_bfloat16* __restrict__ W,
    const float* __restrict__ bias,
    const __hip_bfloat16* __restrict__ A2,
    const __hip_bfloat16* __restrict__ W2,
    const float* __restrict__ bias2,
    __hip_bfloat16* __restrict__ Cb,
    __hip_bfloat16* __restrict__ Cb2,
    int Ndim, int Kdim, int kLen)
{
  __shared__ char lds[32768];  // A: buf*8192, W: 16384 + buf*8192
  const int tid = threadIdx.x, wave = tid >> 6, lane = tid & 63;
  const int rl = lane & 15, gq = lane >> 4;
  const int wr = wave >> 1, wc = wave & 1;

  const int nwg = gridDim.x * gridDim.y;
  const int lin = blockIdx.y * gridDim.x + blockIdx.x;
  const int swz = (lin & 7) * (nwg >> 3) + (lin >> 3);
  const int bx = swz % gridDim.x, by = swz / gridDim.x;

  const int row0 = by * 128;
  const int col0 = bx * 128;

  const __hip_bfloat16* Ap = A;
  const __hip_bfloat16* Wp = W;
  const float* bp = bias;
  int kOff = blockIdx.z * kLen;
  if (STORE == 3) {
    kOff = 0;
    if (blockIdx.z) { Ap = A2; Wp = W2; bp = bias2; }
  }

  f32x4 acc[4][4] = {};
  const int ntiles = kLen >> 5;

  auto stage = [&](int kt, int d) {
    const int kbase = kOff + (kt << 5);
    #pragma unroll
    for (int r = 0; r < 2; ++r) {
      int p = r * 4096 + tid * 16;
      int R = p >> 6, c = (p >> 4) & 3;
      int gc = c ^ ((R >> 1) & 3);
      const __hip_bfloat16* srcA = Ap + (size_t)(row0 + R) * Kdim + kbase + gc * 8;
      __builtin_amdgcn_global_load_lds(
          (const __attribute__((address_space(1))) void*)srcA,
          (__attribute__((address_space(3))) void*)(lds + d * 8192 + p), 16, 0, 0);
      const __hip_bfloat16* srcW = Wp + (size_t)(col0 + R) * Kdim + kbase + gc * 8;
      __builtin_amdgcn_global_load_lds(
          (const __attribute__((address_space(1))) void*)srcW,
          (__attribute__((address_space(3))) void*)(lds + 16384 + d * 8192 + p), 16, 0, 0);
    }
  };

  stage(0, 0);
  __syncthreads();  // tile 0 resident
  for (int kt = 0; kt < ntiles; ++kt) {
    const int d = kt & 1;
    if (kt + 1 < ntiles) stage(kt + 1, d ^ 1);  // issue early, fly under MFMA

    short8 aF[4], bF[4];
    #pragma unroll
    for (int m = 0; m < 4; ++m) {
      int rr = wr * 64 + m * 16 + rl;
      aF[m] = *(const short8*)(lds + d * 8192 + rr * 64 + ((gq ^ ((rr >> 1) & 3)) << 4));
    }
    #pragma unroll
    for (int n = 0; n < 4; ++n) {
      int rr = wc * 64 + n * 16 + rl;
      bF[n] = *(const short8*)(lds + 16384 + d * 8192 + rr * 64 + ((gq ^ ((rr >> 1) & 3)) << 4));
    }
    __builtin_amdgcn_s_setprio(1);
    #pragma unroll
    for (int m = 0; m < 4; ++m)
      #pragma unroll
      for (int n = 0; n < 4; ++n)
        acc[m][n] = __builtin_amdgcn_mfma_f32_16x16x32_bf16(aF[m], bF[n], acc[m][n], 0, 0, 0);
    __builtin_amdgcn_s_setprio(0);
    __syncthreads();  // next tile landed + all reads of buf d done
  }

  // ---------------- coalesced epilogue (LDS re-layout) ----------------
  char* sw = lds + wave * 8192;  // per-wave 64 rows * 128B scratch
  const bool vt = (STORE == 3) && (blockIdx.z == 1);
  const bool addb = (STORE == 3) ? true : ((bias != nullptr) && (blockIdx.z == 0));
  float bvv[4];
  #pragma unroll
  for (int n = 0; n < 4; ++n)
    bvv[n] = addb ? bp[col0 + wc * 64 + n * 16 + rl] : 0.0f;

  #pragma unroll
  for (int n = 0; n < 4; ++n)
    #pragma unroll
    for (int m = 0; m < 4; ++m)
      #pragma unroll
      for (int j = 0; j < 4; ++j) {
        float val = acc[m][n][j] + bvv[n];
        if (RELU) val = fmaxf(val, 0.0f);
        int addr;
        if (vt) {
          int orow = n * 16 + rl, ocol = m * 16 + gq * 4 + j;
          addr = orow * 128 + ((ocol * 2) ^ ((orow & 7) << 4));
        } else {
          int orow = m * 16 + gq * 4 + j;
          addr = orow * 128 + (((n * 16 + rl) * 2) ^ (((orow >> 1) & 7) << 4));
        }
        *(unsigned short*)(sw + addr) = f2b(val);
      }
  asm volatile("s_waitcnt lgkmcnt(0)" ::: "memory");
  __builtin_amdgcn_sched_barrier(0);

  __hip_bfloat16* Cbd = blockIdx.z ? Cb2 : Cb;
  const int cchunk = lane & 7;
  if (vt) {
    const int bh64 = ((row0 >> 9) * 8 + (col0 >> 6) + wc) * 64;
    const int tbase = (row0 & 511) + wr * 64;
    #pragma unroll
    for (int it = 0; it < 8; ++it) {
      int d0 = it * 8 + (lane >> 3);
      uint4 vv = *(const uint4*)(sw + d0 * 128 + ((cchunk * 16) ^ ((d0 & 7) << 4)));
      *(uint4*)((char*)Cbd + ((size_t)(bh64 + d0) * 512 + tbase) * 2 + cchunk * 16) = vv;
    }
  } else {
    #pragma unroll
    for (int it = 0; it < 8; ++it) {
      int orow = it * 8 + (lane >> 3);
      uint4 vv = *(const uint4*)(sw + orow * 128 + ((cchunk * 16) ^ (((orow >> 1) & 7) << 4)));
      *(uint4*)((char*)Cbd + ((size_t)(row0 + wr * 64 + orow) * Ndim + col0 + wc * 64) * 2 +
                cchunk * 16) = vv;
    }
  }
}

// ---------------- flash attention: swapped-QK^T, in-register softmax ---------
// grid 256 = (b,h), 512 thr. Block stages K[512][64] + vT[64][512] once
// (128KB LDS, chunk-XOR swizzles), then 8 waves run barrier-free. Wave w owns
// q-tiles {w, 15-w}; swapped 32x32x16 MFMAs put q on the output COLUMN so
// softmax state is lane-scalar; P repacked in-register into PV's B-operand.
// T13 defer-max: skip O-rescale while tile max stays within +8 of running max.
__global__ __launch_bounds__(512, 2) void fattn_kernel(
    const __hip_bfloat16* __restrict__ kq,  // [B*S, D]
    const __hip_bfloat16* __restrict__ vT,  // [(b*8+h)*64+d][t]
    const float* __restrict__ fr,           // [B*S]
    __hip_bfloat16* __restrict__ ctx)       // [B*S, D]
{
  __shared__ char lds[131072];  // K [0,64K) ck^(r&7); vT [64K,128K) ck^(d&15)
  const int tid = threadIdx.x, wave = tid >> 6, lane = tid & 63;
  const int lq = lane & 31, hi = lane >> 5;
  const int bh = blockIdx.x;
  const int b = bh >> 3, h = bh & 7;
  const size_t kqbase = ((size_t)b * S_) * D_ + h * DK_;
  const size_t vtbase = ((size_t)bh * DK_) * S_;
  const char* kg = (const char*)kq + kqbase * 2;
  const char* vg = (const char*)vT + vtbase * 2;

  #pragma unroll
  for (int i = 0; i < 8; ++i) {
    int p = i * 8192 + tid * 16;
    int r = p >> 7, ck = (p >> 4) & 7;
    __builtin_amdgcn_global_load_lds(
        (const __attribute__((address_space(1))) void*)(kg + (size_t)r * 1024 + ((ck ^ (r & 7)) << 4)),
        (__attribute__((address_space(3))) void*)(lds + p), 16, 0, 0);
  }
  #pragma unroll
  for (int i = 0; i < 8; ++i) {
    int p = i * 8192 + tid * 16;
    int d = p >> 10, ck = (p >> 4) & 63;
    __builtin_amdgcn_global_load_lds(
        (const __attribute__((address_space(1))) void*)(vg + (size_t)d * 1024 + ((ck ^ (d & 15)) << 4)),
        (__attribute__((address_space(3))) void*)(lds + 65536 + p), 16, 0, 0);
  }

  const int qia = wave, qib = 15 - wave;
  const int na = qia + 1, nb = qib + 1;
  const int sa = qia * 32 + lq, sb = qib * 32 + lq;
  const float sfa = fr[b * S_ + sa] * 0.125f;
  const float sfb = fr[b * S_ + sb] * 0.125f;

  asm volatile("s_waitcnt vmcnt(0)" ::: "memory");
  __builtin_amdgcn_sched_barrier(0);
  __builtin_amdgcn_s_barrier();

  short8 qa_[4], qb_[4];
  #pragma unroll
  for (int f = 0; f < 4; ++f) {
    qa_[f] = *(const short8*)(lds + sa * 128 + ((((f << 1) + hi) ^ (sa & 7)) << 4));
    qb_[f] = *(const short8*)(lds + sb * 128 + ((((f << 1) + hi) ^ (sb & 7)) << 4));
  }

  f32x16 oa0 = {}, oa1 = {}, ob0 = {}, ob1 = {};
  float ma = -3.0e38f, la = 0.0f, mb = -3.0e38f, lb = 0.0f;

  auto process = [&](f32x16& o0, f32x16& o1, float& m, float& l,
                     const short8* qf, int srow, float sf,
                     const short8* kb, const short8* vb0, const short8* vb1,
                     int t0) {
    f32x16 s = {};
    #pragma unroll
    for (int f = 0; f < 4; ++f)
      s = __builtin_amdgcn_mfma_f32_32x32x16_bf16(kb[f], qf[f], s, 0, 0, 0);
    float p[16];
    #pragma unroll
    for (int r = 0; r < 16; ++r) {
      int tg = t0 + (r & 3) + 8 * (r >> 2) + 4 * hi;
      float v = s[r] * sf;
      p[r] = (tg >= srow) ? -3.0e38f : v;
    }
    float t8[8], t4[4];
    #pragma unroll
    for (int i = 0; i < 8; ++i) t8[i] = fmaxf(p[2 * i], p[2 * i + 1]);
    #pragma unroll
    for (int i = 0; i < 4; ++i) t4[i] = fmaxf(t8[2 * i], t8[2 * i + 1]);
    float mt = fmaxf(fmaxf(t4[0], t4[1]), fmaxf(t4[2], t4[3]));
    mt = fmaxf(mt, __shfl_xor(mt, 32));
    // T13 defer-max: rescale only when tile max grows past m+8
    if (!__all(mt <= m + 8.0f)) {
      float mn = fmaxf(m, mt);
      float fac = __expf(m - mn);
      m = mn;
      l *= fac;
      #pragma unroll
      for (int i = 0; i < 16; ++i) { o0[i] *= fac; o1[i] *= fac; }
    }
    #pragma unroll
    for (int r = 0; r < 16; ++r) p[r] = __expf(p[r] - m);
    float s8[8], s4[4];
    #pragma unroll
    for (int i = 0; i < 8; ++i) s8[i] = p[2 * i] + p[2 * i + 1];
    #pragma unroll
    for (int i = 0; i < 4; ++i) s4[i] = s8[2 * i] + s8[2 * i + 1];
    float ps = (s4[0] + s4[1]) + (s4[2] + s4[3]);
    ps += __shfl_xor(ps, 32);
    l += ps;
    #pragma unroll
    for (int c = 0; c < 2; ++c) {
      unsigned X0 = pkbf(p[8 * c + 0], p[8 * c + 1]);
      unsigned X1 = pkbf(p[8 * c + 2], p[8 * c + 3]);
      unsigned Y0 = pkbf(p[8 * c + 4], p[8 * c + 5]);
      unsigned Y1 = pkbf(p[8 * c + 6], p[8 * c + 7]);
      unsigned z0 = hi ? X0 : Y0, z1 = hi ? X1 : Y1;
      unsigned r0 = __shfl_xor(z0, 32), r1 = __shfl_xor(z1, 32);
      union { unsigned u[4]; short8 v; } pb;
      pb.u[0] = hi ? r0 : X0;
      pb.u[1] = hi ? r1 : X1;
      pb.u[2] = hi ? Y0 : r0;
      pb.u[3] = hi ? Y1 : r1;
      o0 = __builtin_amdgcn_mfma_f32_32x32x16_bf16(vb0[c], pb.v, o0, 0, 0, 0);
      o1 = __builtin_amdgcn_mfma_f32_32x32x16_bf16(vb1[c], pb.v, o1, 0, 0, 0);
    }
  };

  for (int ti = 0; ti < nb; ++ti) {
    const int t0 = ti * 32;
    short8 kb[4];
    #pragma unroll
    for (int f = 0; f < 4; ++f) {
      int tw = t0 + lq;
      kb[f] = *(const short8*)(lds + tw * 128 + ((((f << 1) + hi) ^ (tw & 7)) << 4));
    }
    short8 vb0[2], vb1[2];
    #pragma unroll
    for (int c = 0; c < 2; ++c) {
      int ck = 4 * ti + 2 * c + hi;
      int d0 = lq;
      vb0[c] = *(const short8*)(lds + 65536 + d0 * 1024 + ((ck ^ (d0 & 15)) << 4));
      int d1 = 32 + lq;
      vb1[c] = *(const short8*)(lds + 65536 + d1 * 1024 + ((ck ^ (d1 & 15)) << 4));
    }
    if (ti < na) process(oa0, oa1, ma, la, qa_, sa, sfa, kb, vb0, vb1, t0);
    process(ob0, ob1, mb, lb, qb_, sb, sfb, kb, vb0, vb1, t0);
  }

  auto writeO = [&](const f32x16& o0, const f32x16& o1, float l, int srow) {
    float inv = (srow == 0) ? 0.0f : 1.0f / l;
    char* base = (char*)ctx + (((size_t)(b * S_ + srow)) * D_ + h * DK_) * 2;
    #pragma unroll
    for (int gg = 0; gg < 4; ++gg) {
      uint2 w0, w1;
      w0.x = pkbf(o0[4 * gg + 0] * inv, o0[4 * gg + 1] * inv);
      w0.y = pkbf(o0[4 * gg + 2] * inv, o0[4 * gg + 3] * inv);
      *(uint2*)(base + (8 * gg + 4 * hi) * 2) = w0;
      w1.x = pkbf(o1[4 * gg + 0] * inv, o1[4 * gg + 1] * inv);
      w1.y = pkbf(o1[4 * gg + 2] * inv, o1[4 * gg + 3] * inv);
      *(uint2*)(base + (32 + 8 * gg + 4 * hi) * 2) = w1;
    }
  };
  writeO(oa0, oa1, la, sa);
  writeO(ob0, ob1, lb, sb);
}

// ---------------- fused residual + LayerNorm (bf16 streams) ------------------
template<int NADD, int FINAL>
__global__ __launch_bounds__(256) void ln_kernel(
    const uint4* __restrict__ xres, const uint4* __restrict__ add,
    const uint4* __restrict__ add2,
    const float* __restrict__ g, const float* __restrict__ bta,
    uint4* __restrict__ xb_out, float4* __restrict__ xf_out)
{
  const int lane = threadIdx.x & 63, wv = threadIdx.x >> 6;
  const size_t row = (size_t)blockIdx.x * 4 + wv;

  uint4 xr = xres[row * 64 + lane];
  uint4 ab = add[row * 64 + lane];
  const unsigned short* xp = (const unsigned short*)&xr;
  const unsigned short* ap = (const unsigned short*)&ab;
  float v[8];
  #pragma unroll
  for (int i = 0; i < 8; ++i) v[i] = b2f(xp[i]) + b2f(ap[i]);
  if (NADD == 2) {
    uint4 ab2 = add2[row * 64 + lane];
    const unsigned short* ap2 = (const unsigned short*)&ab2;
    #pragma unroll
    for (int i = 0; i < 8; ++i) v[i] += b2f(ap2[i]);
  }
  float s = 0.0f;
  #pragma unroll
  for (int i = 0; i < 8; ++i) s += v[i];
  s = waveReduceSum(s);
  float mu = s * (1.0f / 512.0f);
  float vs = 0.0f;
  #pragma unroll
  for (int i = 0; i < 8; ++i) { float dd = v[i] - mu; vs += dd * dd; }
  vs = waveReduceSum(vs);
  float rstd = rsqrtf(vs * (1.0f / 512.0f) + 1e-5f);

  const int c0i = lane * 8;
  float4 gg0 = *(const float4*)(g + c0i), gg1 = *(const float4*)(g + c0i + 4);
  float4 bb0 = *(const float4*)(bta + c0i), bb1 = *(const float4*)(bta + c0i + 4);
  float o[8];
  o[0] = (v[0] - mu) * rstd * gg0.x + bb0.x;
  o[1] = (v[1] - mu) * rstd * gg0.y + bb0.y;
  o[2] = (v[2] - mu) * rstd * gg0.z + bb0.z;
  o[3] = (v[3] - mu) * rstd * gg0.w + bb0.w;
  o[4] = (v[4] - mu) * rstd * gg1.x + bb1.x;
  o[5] = (v[5] - mu) * rstd * gg1.y + bb1.y;
  o[6] = (v[6] - mu) * rstd * gg1.z + bb1.z;
  o[7] = (v[7] - mu) * rstd * gg1.w + bb1.w;

  if (FINAL) {
    float4 w0, w1;
    w0.x = o[0]; w0.y = o[1]; w0.z = o[2]; w0.w = o[3];
    w1.x = o[4]; w1.y = o[5]; w1.z = o[6]; w1.w = o[7];
    xf_out[row * 128 + lane * 2] = w0;
    xf_out[row * 128 + lane * 2 + 1] = w1;
  } else {
    uint4 pw;
    pw.x = pkbf(o[0], o[1]);
    pw.y = pkbf(o[2], o[3]);
    pw.z = pkbf(o[4], o[5]);
    pw.w = pkbf(o[6], o[7]);
    xb_out[row * 64 + lane] = pw;
  }
}

// ---------------- launcher ---------------------------------------------------
extern "C" void kernel_launch(void* const* d_in, const int* in_sizes, int n_in,
                              void* d_out, int out_size, void* d_ws, size_t ws_size,
                              hipStream_t stream) {
  (void)in_sizes; (void)n_in; (void)out_size; (void)ws_size;
  const float* q   = (const float*)d_in[0];
  const float* qa  = (const float*)d_in[1];
  const float* frr = (const float*)d_in[2];
  const float* pos = (const float*)d_in[3];
  const float* Wk  = (const float*)d_in[4];
  const float* bk  = (const float*)d_in[5];
  const float* Wv  = (const float*)d_in[6];
  const float* bv  = (const float*)d_in[7];
  const float* Wo  = (const float*)d_in[8];
  const float* bo  = (const float*)d_in[9];
  const float* W1  = (const float*)d_in[10];
  const float* b1  = (const float*)d_in[11];
  const float* W2  = (const float*)d_in[12];
  const float* b2  = (const float*)d_in[13];
  const float* g1  = (const float*)d_in[14];
  const float* be1 = (const float*)d_in[15];
  const float* g2  = (const float*)d_in[16];
  const float* be2 = (const float*)d_in[17];

  char* ws = (char*)d_ws;
  __hip_bfloat16* xb   = (__hip_bfloat16*)(ws + 33554432);
  __hip_bfloat16* yb   = (__hip_bfloat16*)(ws + 50331648);
  __hip_bfloat16* kqb  = (__hip_bfloat16*)(ws + 67108864);
  __hip_bfloat16* vtb  = (__hip_bfloat16*)(ws + 83886080);
  __hip_bfloat16* ctxb = (__hip_bfloat16*)(ws + 100663296);
  __hip_bfloat16* hb   = (__hip_bfloat16*)(ws + 117440512);     // 67.1 MB
  __hip_bfloat16* wkb  = (__hip_bfloat16*)(ws + 184549376);     // contiguous ->
  __hip_bfloat16* wvb  = (__hip_bfloat16*)(ws + 186646528);
  __hip_bfloat16* wob  = (__hip_bfloat16*)(ws + 188743680);
  __hip_bfloat16* w1b  = (__hip_bfloat16*)(ws + 190840832);
  __hip_bfloat16* w2b  = (__hip_bfloat16*)(ws + 199229440);     // ends 207618048
  // dead-region reuse (per-layer lifetimes):
  __hip_bfloat16* obf = (__hip_bfloat16*)(ws + 67108864);   // over kqb (dead post-fattn)
  __hip_bfloat16* pf0 = (__hip_bfloat16*)(ws + 83886080);   // over vtb (dead post-fattn)
  __hip_bfloat16* pf1 = (__hip_bfloat16*)(ws + 100663296);  // over ctxb (dead post-projO)

  prep_kernel<<<8192, 256, 0, stream>>>((const float4*)q, (const float4*)qa,
                                        (const float4*)pos, (uint2*)xb, (uint2*)yb);
  cast_all_kernel<<<11264, 256, 0, stream>>>(
      (const float4*)Wk, (const float4*)Wv, (const float4*)Wo,
      (const float4*)W1, (const float4*)W2, (uint2*)wkb);

  for (int l = 0; l < L_; ++l) {
    // fused K-proj (z=0, row-major) + V-proj (z=1, vT transposed)
    gemm128_kernel<0,3><<<dim3(4, 128, 2), 256, 0, stream>>>(
        xb, wkb + (size_t)l * 262144, bk + l * 512,
        yb, wvb + (size_t)l * 262144, bv + l * 512,
        kqb, vtb, 512, 512, 512);
    fattn_kernel<<<256, 512, 0, stream>>>(kqb, vtb, frr, ctxb);
    gemm128_kernel<0,0><<<dim3(4, 128, 1), 256, 0, stream>>>(
        ctxb, wob + (size_t)l * 262144, bo + l * 512,
        nullptr, nullptr, nullptr, obf, nullptr, 512, 512, 512);
    // residual + LN1 (bf16 in-place)
    ln_kernel<1,0><<<4096, 256, 0, stream>>>(
        (const uint4*)xb, (const uint4*)obf, nullptr,
        g1 + l * 512, be1 + l * 512, (uint4*)xb, nullptr);
    // FFN1 (ReLU)
    gemm128_kernel<1,0><<<dim3(16, 128, 1), 256, 0, stream>>>(
        xb, w1b + (size_t)l * 1048576, b1 + l * 2048,
        nullptr, nullptr, nullptr, hb, nullptr, 2048, 512, 512);
    // FFN2 split-K=2
    gemm128_kernel<0,0><<<dim3(4, 128, 2), 256, 0, stream>>>(
        hb, w2b + (size_t)l * 1048576, b2 + l * 512,
        nullptr, nullptr, nullptr, pf0, pf1, 512, 2048, 1024);
    // residual + LN2 (bf16 in-place; last layer writes f32 d_out)
    if (l == L_ - 1) {
      ln_kernel<2,1><<<4096, 256, 0, stream>>>(
          (const uint4*)xb, (const uint4*)pf0, (const uint4*)pf1,
          g2 + l * 512, be2 + l * 512, nullptr, (float4*)d_out);
    } else {
      ln_kernel<2,0><<<4096, 256, 0, stream>>>(
          (const uint4*)xb, (const uint4*)pf0, (const uint4*)pf1,
          g2 + l * 512, be2 + l * 512, (uint4*)xb, nullptr);
    }
  }
}

// Round 18
// 722.140 us; speedup vs baseline: 1.0457x; 1.0003x over previous
//
#include <hip/hip_runtime.h>
#include <hip/hip_bf16.h>

// Problem constants
constexpr int B_ = 32, S_ = 512, D_ = 512, H_ = 8, L_ = 4, F_ = 2048, DK_ = 64;

typedef __attribute__((ext_vector_type(8))) short short8;
typedef __attribute__((ext_vector_type(4))) float f32x4;
typedef __attribute__((ext_vector_type(16))) float f32x16;

__device__ inline unsigned short f2b(float f) {
  union { __hip_bfloat16 h; unsigned short u; } cv;
  cv.h = __float2bfloat16(f);
  return cv.u;
}
__device__ inline float b2f(unsigned short u) {
  union { unsigned int i; float f; } c;
  c.i = ((unsigned int)u) << 16;
  return c.f;
}
__device__ inline unsigned pkbf(float a, float b) {
  unsigned r;
  asm("v_cvt_pk_bf16_f32 %0, %1, %2" : "=v"(r) : "v"(a), "v"(b));
  return r;
}
__device__ inline float waveReduceSum(float v) {
  #pragma unroll
  for (int o = 32; o > 0; o >>= 1) v += __shfl_xor(v, o);
  return v;
}

// ---------------- prep: xb = bf16(q + pos), yb = bf16(qa + pos) --------------
__global__ void prep_kernel(const float4* __restrict__ q, const float4* __restrict__ qa,
                            const float4* __restrict__ pos,
                            uint2* __restrict__ xb, uint2* __restrict__ yb) {
  int i = blockIdx.x * blockDim.x + threadIdx.x;  // 2,097,152 exact
  float4 p = pos[i & 65535];
  float4 a = q[i], c = qa[i];
  uint2 px, py;
  px.x = pkbf(a.x + p.x, a.y + p.y);
  px.y = pkbf(a.z + p.z, a.w + p.w);
  py.x = pkbf(c.x + p.x, c.y + p.y);
  py.y = pkbf(c.z + p.z, c.w + p.w);
  xb[i] = px;
  yb[i] = py;
}

// ---------------- fused cast of ALL weights (dst is contiguous) --------------
__global__ void cast_all_kernel(const float4* __restrict__ wk, const float4* __restrict__ wv,
                                const float4* __restrict__ wo, const float4* __restrict__ w1,
                                const float4* __restrict__ w2, uint2* __restrict__ dst) {
  int i = blockIdx.x * blockDim.x + threadIdx.x;  // 0..2883583 exact
  const float4* s;
  int off;
  if (i < 786432) {
    if (i < 262144) { s = wk; off = i; }
    else if (i < 524288) { s = wv; off = i - 262144; }
    else { s = wo; off = i - 524288; }
  } else if (i < 1835008) {
    s = w1; off = i - 786432;
  } else {
    s = w2; off = i - 1835008;
  }
  float4 v = s[off];
  uint2 p;
  p.x = pkbf(v.x, v.y);
  p.y = pkbf(v.z, v.w);
  dst[i] = p;
}

// ---------------- 128x128 MFMA GEMM, 2-phase dbuf, 32KB LDS ------------------
// STORE 0: bf16 row-major (z picks Cb/Cb2, bias only z==0).
// STORE 3: dual-GEMM — z==0: A/W/bias -> Cb row-major;
//                      z==1: A2/W2/bias2 -> Cb2 vT[((b*8+h)*64+d)*512+t].
template<int RELU, int STORE>
__global__ __launch_bounds__(256, 2) void gemm128_kernel(
    const __hip_bfloat16* __restrict__ A,
    const __hip_bfloat16* __restrict__ W,
    const float* __restrict__ bias,
    const __hip_bfloat16* __restrict__ A2,
    const __hip_bfloat16* __restrict__ W2,
    const float* __restrict__ bias2,
    __hip_bfloat16* __restrict__ Cb,
    __hip_bfloat16* __restrict__ Cb2,
    int Ndim, int Kdim, int kLen)
{
  __shared__ char lds[32768];  // A: buf*8192, W: 16384 + buf*8192
  const int tid = threadIdx.x, wave = tid >> 6, lane = tid & 63;
  const int rl = lane & 15, gq = lane >> 4;
  const int wr = wave >> 1, wc = wave & 1;

  const int nwg = gridDim.x * gridDim.y;
  const int lin = blockIdx.y * gridDim.x + blockIdx.x;
  const int swz = (lin & 7) * (nwg >> 3) + (lin >> 3);
  const int bx = swz % gridDim.x, by = swz / gridDim.x;

  const int row0 = by * 128;
  const int col0 = bx * 128;

  const __hip_bfloat16* Ap = A;
  const __hip_bfloat16* Wp = W;
  const float* bp = bias;
  int kOff = blockIdx.z * kLen;
  if (STORE == 3) {
    kOff = 0;
    if (blockIdx.z) { Ap = A2; Wp = W2; bp = bias2; }
  }

  f32x4 acc[4][4] = {};
  const int ntiles = kLen >> 5;

  auto stage = [&](int kt, int d) {
    const int kbase = kOff + (kt << 5);
    #pragma unroll
    for (int r = 0; r < 2; ++r) {
      int p = r * 4096 + tid * 16;
      int R = p >> 6, c = (p >> 4) & 3;
      int gc = c ^ ((R >> 1) & 3);
      const __hip_bfloat16* srcA = Ap + (size_t)(row0 + R) * Kdim + kbase + gc * 8;
      __builtin_amdgcn_global_load_lds(
          (const __attribute__((address_space(1))) void*)srcA,
          (__attribute__((address_space(3))) void*)(lds + d * 8192 + p), 16, 0, 0);
      const __hip_bfloat16* srcW = Wp + (size_t)(col0 + R) * Kdim + kbase + gc * 8;
      __builtin_amdgcn_global_load_lds(
          (const __attribute__((address_space(1))) void*)srcW,
          (__attribute__((address_space(3))) void*)(lds + 16384 + d * 8192 + p), 16, 0, 0);
    }
  };

  stage(0, 0);
  __syncthreads();  // tile 0 resident
  for (int kt = 0; kt < ntiles; ++kt) {
    const int d = kt & 1;
    if (kt + 1 < ntiles) stage(kt + 1, d ^ 1);  // issue early, fly under MFMA

    short8 aF[4], bF[4];
    #pragma unroll
    for (int m = 0; m < 4; ++m) {
      int rr = wr * 64 + m * 16 + rl;
      aF[m] = *(const short8*)(lds + d * 8192 + rr * 64 + ((gq ^ ((rr >> 1) & 3)) << 4));
    }
    #pragma unroll
    for (int n = 0; n < 4; ++n) {
      int rr = wc * 64 + n * 16 + rl;
      bF[n] = *(const short8*)(lds + 16384 + d * 8192 + rr * 64 + ((gq ^ ((rr >> 1) & 3)) << 4));
    }
    __builtin_amdgcn_s_setprio(1);
    #pragma unroll
    for (int m = 0; m < 4; ++m)
      #pragma unroll
      for (int n = 0; n < 4; ++n)
        acc[m][n] = __builtin_amdgcn_mfma_f32_16x16x32_bf16(aF[m], bF[n], acc[m][n], 0, 0, 0);
    __builtin_amdgcn_s_setprio(0);
    __syncthreads();  // next tile landed + all reads of buf d done
  }

  // ---------------- coalesced epilogue (LDS re-layout) ----------------
  char* sw = lds + wave * 8192;  // per-wave 64 rows * 128B scratch
  const bool vt = (STORE == 3) && (blockIdx.z == 1);
  const bool addb = (STORE == 3) ? true : ((bias != nullptr) && (blockIdx.z == 0));
  float bvv[4];
  #pragma unroll
  for (int n = 0; n < 4; ++n)
    bvv[n] = addb ? bp[col0 + wc * 64 + n * 16 + rl] : 0.0f;

  #pragma unroll
  for (int n = 0; n < 4; ++n)
    #pragma unroll
    for (int m = 0; m < 4; ++m)
      #pragma unroll
      for (int j = 0; j < 4; ++j) {
        float val = acc[m][n][j] + bvv[n];
        if (RELU) val = fmaxf(val, 0.0f);
        int addr;
        if (vt) {
          int orow = n * 16 + rl, ocol = m * 16 + gq * 4 + j;
          addr = orow * 128 + ((ocol * 2) ^ ((orow & 7) << 4));
        } else {
          int orow = m * 16 + gq * 4 + j;
          addr = orow * 128 + (((n * 16 + rl) * 2) ^ (((orow >> 1) & 7) << 4));
        }
        *(unsigned short*)(sw + addr) = f2b(val);
      }
  asm volatile("s_waitcnt lgkmcnt(0)" ::: "memory");
  __builtin_amdgcn_sched_barrier(0);

  __hip_bfloat16* Cbd = blockIdx.z ? Cb2 : Cb;
  const int cchunk = lane & 7;
  if (vt) {
    const int bh64 = ((row0 >> 9) * 8 + (col0 >> 6) + wc) * 64;
    const int tbase = (row0 & 511) + wr * 64;
    #pragma unroll
    for (int it = 0; it < 8; ++it) {
      int d0 = it * 8 + (lane >> 3);
      uint4 vv = *(const uint4*)(sw + d0 * 128 + ((cchunk * 16) ^ ((d0 & 7) << 4)));
      *(uint4*)((char*)Cbd + ((size_t)(bh64 + d0) * 512 + tbase) * 2 + cchunk * 16) = vv;
    }
  } else {
    #pragma unroll
    for (int it = 0; it < 8; ++it) {
      int orow = it * 8 + (lane >> 3);
      uint4 vv = *(const uint4*)(sw + orow * 128 + ((cchunk * 16) ^ (((orow >> 1) & 7) << 4)));
      *(uint4*)((char*)Cbd + ((size_t)(row0 + wr * 64 + orow) * Ndim + col0 + wc * 64) * 2 +
                cchunk * 16) = vv;
    }
  }
}

// ---------------- flash attention: swapped-QK^T, in-register softmax ---------
// grid 256 = (b,h), 512 thr. Block stages K[512][64] + vT[64][512] once
// (128KB LDS, chunk-XOR swizzles), then 8 waves run barrier-free. Wave w owns
// q-tiles {w, 15-w}; swapped 32x32x16 MFMAs put q on the output COLUMN so
// softmax state is lane-scalar; P repacked in-register into PV's B-operand.
// T13 defer-max; T5 setprio around MFMA clusters; T17 max3-friendly reduce.
__global__ __launch_bounds__(512, 2) void fattn_kernel(
    const __hip_bfloat16* __restrict__ kq,  // [B*S, D]
    const __hip_bfloat16* __restrict__ vT,  // [(b*8+h)*64+d][t]
    const float* __restrict__ fr,           // [B*S]
    __hip_bfloat16* __restrict__ ctx)       // [B*S, D]
{
  __shared__ char lds[131072];  // K [0,64K) ck^(r&7); vT [64K,128K) ck^(d&15)
  const int tid = threadIdx.x, wave = tid >> 6, lane = tid & 63;
  const int lq = lane & 31, hi = lane >> 5;
  const int bh = blockIdx.x;
  const int b = bh >> 3, h = bh & 7;
  const size_t kqbase = ((size_t)b * S_) * D_ + h * DK_;
  const size_t vtbase = ((size_t)bh * DK_) * S_;
  const char* kg = (const char*)kq + kqbase * 2;
  const char* vg = (const char*)vT + vtbase * 2;

  #pragma unroll
  for (int i = 0; i < 8; ++i) {
    int p = i * 8192 + tid * 16;
    int r = p >> 7, ck = (p >> 4) & 7;
    __builtin_amdgcn_global_load_lds(
        (const __attribute__((address_space(1))) void*)(kg + (size_t)r * 1024 + ((ck ^ (r & 7)) << 4)),
        (__attribute__((address_space(3))) void*)(lds + p), 16, 0, 0);
  }
  #pragma unroll
  for (int i = 0; i < 8; ++i) {
    int p = i * 8192 + tid * 16;
    int d = p >> 10, ck = (p >> 4) & 63;
    __builtin_amdgcn_global_load_lds(
        (const __attribute__((address_space(1))) void*)(vg + (size_t)d * 1024 + ((ck ^ (d & 15)) << 4)),
        (__attribute__((address_space(3))) void*)(lds + 65536 + p), 16, 0, 0);
  }

  const int qia = wave, qib = 15 - wave;
  const int na = qia + 1, nb = qib + 1;
  const int sa = qia * 32 + lq, sb = qib * 32 + lq;
  const float sfa = fr[b * S_ + sa] * 0.125f;
  const float sfb = fr[b * S_ + sb] * 0.125f;

  asm volatile("s_waitcnt vmcnt(0)" ::: "memory");
  __builtin_amdgcn_sched_barrier(0);
  __builtin_amdgcn_s_barrier();

  short8 qa_[4], qb_[4];
  #pragma unroll
  for (int f = 0; f < 4; ++f) {
    qa_[f] = *(const short8*)(lds + sa * 128 + ((((f << 1) + hi) ^ (sa & 7)) << 4));
    qb_[f] = *(const short8*)(lds + sb * 128 + ((((f << 1) + hi) ^ (sb & 7)) << 4));
  }

  f32x16 oa0 = {}, oa1 = {}, ob0 = {}, ob1 = {};
  float ma = -3.0e38f, la = 0.0f, mb = -3.0e38f, lb = 0.0f;

  auto process = [&](f32x16& o0, f32x16& o1, float& m, float& l,
                     const short8* qf, int srow, float sf,
                     const short8* kb, const short8* vb0, const short8* vb1,
                     int t0) {
    f32x16 s = {};
    __builtin_amdgcn_s_setprio(1);
    #pragma unroll
    for (int f = 0; f < 4; ++f)
      s = __builtin_amdgcn_mfma_f32_32x32x16_bf16(kb[f], qf[f], s, 0, 0, 0);
    __builtin_amdgcn_s_setprio(0);
    float p[16];
    #pragma unroll
    for (int r = 0; r < 16; ++r) {
      int tg = t0 + (r & 3) + 8 * (r >> 2) + 4 * hi;
      float v = s[r] * sf;
      p[r] = (tg >= srow) ? -3.0e38f : v;
    }
    // max tree in fmax3-fusable triples: 16 -> 6 -> 2 -> 1
    float u0 = fmaxf(fmaxf(p[0], p[1]), p[2]);
    float u1 = fmaxf(fmaxf(p[3], p[4]), p[5]);
    float u2 = fmaxf(fmaxf(p[6], p[7]), p[8]);
    float u3 = fmaxf(fmaxf(p[9], p[10]), p[11]);
    float u4 = fmaxf(fmaxf(p[12], p[13]), p[14]);
    float w0 = fmaxf(fmaxf(u0, u1), u2);
    float w1 = fmaxf(fmaxf(u3, u4), p[15]);
    float mt = fmaxf(w0, w1);
    mt = fmaxf(mt, __shfl_xor(mt, 32));
    // T13 defer-max: rescale only when tile max grows past m+8
    if (!__all(mt <= m + 8.0f)) {
      float mn = fmaxf(m, mt);
      float fac = __expf(m - mn);
      m = mn;
      l *= fac;
      #pragma unroll
      for (int i = 0; i < 16; ++i) { o0[i] *= fac; o1[i] *= fac; }
    }
    #pragma unroll
    for (int r = 0; r < 16; ++r) p[r] = __expf(p[r] - m);
    float s8[8], s4[4];
    #pragma unroll
    for (int i = 0; i < 8; ++i) s8[i] = p[2 * i] + p[2 * i + 1];
    #pragma unroll
    for (int i = 0; i < 4; ++i) s4[i] = s8[2 * i] + s8[2 * i + 1];
    float ps = (s4[0] + s4[1]) + (s4[2] + s4[3]);
    ps += __shfl_xor(ps, 32);
    l += ps;
    #pragma unroll
    for (int c = 0; c < 2; ++c) {
      unsigned X0 = pkbf(p[8 * c + 0], p[8 * c + 1]);
      unsigned X1 = pkbf(p[8 * c + 2], p[8 * c + 3]);
      unsigned Y0 = pkbf(p[8 * c + 4], p[8 * c + 5]);
      unsigned Y1 = pkbf(p[8 * c + 6], p[8 * c + 7]);
      unsigned z0 = hi ? X0 : Y0, z1 = hi ? X1 : Y1;
      unsigned r0 = __shfl_xor(z0, 32), r1 = __shfl_xor(z1, 32);
      union { unsigned u[4]; short8 v; } pb;
      pb.u[0] = hi ? r0 : X0;
      pb.u[1] = hi ? r1 : X1;
      pb.u[2] = hi ? Y0 : r0;
      pb.u[3] = hi ? Y1 : r1;
      __builtin_amdgcn_s_setprio(1);
      o0 = __builtin_amdgcn_mfma_f32_32x32x16_bf16(vb0[c], pb.v, o0, 0, 0, 0);
      o1 = __builtin_amdgcn_mfma_f32_32x32x16_bf16(vb1[c], pb.v, o1, 0, 0, 0);
      __builtin_amdgcn_s_setprio(0);
    }
  };

  for (int ti = 0; ti < nb; ++ti) {
    const int t0 = ti * 32;
    short8 kb[4];
    #pragma unroll
    for (int f = 0; f < 4; ++f) {
      int tw = t0 + lq;
      kb[f] = *(const short8*)(lds + tw * 128 + ((((f << 1) + hi) ^ (tw & 7)) << 4));
    }
    short8 vb0[2], vb1[2];
    #pragma unroll
    for (int c = 0; c < 2; ++c) {
      int ck = 4 * ti + 2 * c + hi;
      int d0 = lq;
      vb0[c] = *(const short8*)(lds + 65536 + d0 * 1024 + ((ck ^ (d0 & 15)) << 4));
      int d1 = 32 + lq;
      vb1[c] = *(const short8*)(lds + 65536 + d1 * 1024 + ((ck ^ (d1 & 15)) << 4));
    }
    if (ti < na) process(oa0, oa1, ma, la, qa_, sa, sfa, kb, vb0, vb1, t0);
    process(ob0, ob1, mb, lb, qb_, sb, sfb, kb, vb0, vb1, t0);
  }

  auto writeO = [&](const f32x16& o0, const f32x16& o1, float l, int srow) {
    float inv = (srow == 0) ? 0.0f : 1.0f / l;
    char* base = (char*)ctx + (((size_t)(b * S_ + srow)) * D_ + h * DK_) * 2;
    #pragma unroll
    for (int gg = 0; gg < 4; ++gg) {
      uint2 w0, w1;
      w0.x = pkbf(o0[4 * gg + 0] * inv, o0[4 * gg + 1] * inv);
      w0.y = pkbf(o0[4 * gg + 2] * inv, o0[4 * gg + 3] * inv);
      *(uint2*)(base + (8 * gg + 4 * hi) * 2) = w0;
      w1.x = pkbf(o1[4 * gg + 0] * inv, o1[4 * gg + 1] * inv);
      w1.y = pkbf(o1[4 * gg + 2] * inv, o1[4 * gg + 3] * inv);
      *(uint2*)(base + (32 + 8 * gg + 4 * hi) * 2) = w1;
    }
  };
  writeO(oa0, oa1, la, sa);
  writeO(ob0, ob1, lb, sb);
}

// ---------------- fused residual + LayerNorm (bf16 streams) ------------------
template<int NADD, int FINAL>
__global__ __launch_bounds__(256) void ln_kernel(
    const uint4* __restrict__ xres, const uint4* __restrict__ add,
    const uint4* __restrict__ add2,
    const float* __restrict__ g, const float* __restrict__ bta,
    uint4* __restrict__ xb_out, float4* __restrict__ xf_out)
{
  const int lane = threadIdx.x & 63, wv = threadIdx.x >> 6;
  const size_t row = (size_t)blockIdx.x * 4 + wv;

  uint4 xr = xres[row * 64 + lane];
  uint4 ab = add[row * 64 + lane];
  const unsigned short* xp = (const unsigned short*)&xr;
  const unsigned short* ap = (const unsigned short*)&ab;
  float v[8];
  #pragma unroll
  for (int i = 0; i < 8; ++i) v[i] = b2f(xp[i]) + b2f(ap[i]);
  if (NADD == 2) {
    uint4 ab2 = add2[row * 64 + lane];
    const unsigned short* ap2 = (const unsigned short*)&ab2;
    #pragma unroll
    for (int i = 0; i < 8; ++i) v[i] += b2f(ap2[i]);
  }
  float s = 0.0f;
  #pragma unroll
  for (int i = 0; i < 8; ++i) s += v[i];
  s = waveReduceSum(s);
  float mu = s * (1.0f / 512.0f);
  float vs = 0.0f;
  #pragma unroll
  for (int i = 0; i < 8; ++i) { float dd = v[i] - mu; vs += dd * dd; }
  vs = waveReduceSum(vs);
  float rstd = rsqrtf(vs * (1.0f / 512.0f) + 1e-5f);

  const int c0i = lane * 8;
  float4 gg0 = *(const float4*)(g + c0i), gg1 = *(const float4*)(g + c0i + 4);
  float4 bb0 = *(const float4*)(bta + c0i), bb1 = *(const float4*)(bta + c0i + 4);
  float o[8];
  o[0] = (v[0] - mu) * rstd * gg0.x + bb0.x;
  o[1] = (v[1] - mu) * rstd * gg0.y + bb0.y;
  o[2] = (v[2] - mu) * rstd * gg0.z + bb0.z;
  o[3] = (v[3] - mu) * rstd * gg0.w + bb0.w;
  o[4] = (v[4] - mu) * rstd * gg1.x + bb1.x;
  o[5] = (v[5] - mu) * rstd * gg1.y + bb1.y;
  o[6] = (v[6] - mu) * rstd * gg1.z + bb1.z;
  o[7] = (v[7] - mu) * rstd * gg1.w + bb1.w;

  if (FINAL) {
    float4 w0, w1;
    w0.x = o[0]; w0.y = o[1]; w0.z = o[2]; w0.w = o[3];
    w1.x = o[4]; w1.y = o[5]; w1.z = o[6]; w1.w = o[7];
    xf_out[row * 128 + lane * 2] = w0;
    xf_out[row * 128 + lane * 2 + 1] = w1;
  } else {
    uint4 pw;
    pw.x = pkbf(o[0], o[1]);
    pw.y = pkbf(o[2], o[3]);
    pw.z = pkbf(o[4], o[5]);
    pw.w = pkbf(o[6], o[7]);
    xb_out[row * 64 + lane] = pw;
  }
}

// ---------------- launcher ---------------------------------------------------
extern "C" void kernel_launch(void* const* d_in, const int* in_sizes, int n_in,
                              void* d_out, int out_size, void* d_ws, size_t ws_size,
                              hipStream_t stream) {
  (void)in_sizes; (void)n_in; (void)out_size; (void)ws_size;
  const float* q   = (const float*)d_in[0];
  const float* qa  = (const float*)d_in[1];
  const float* frr = (const float*)d_in[2];
  const float* pos = (const float*)d_in[3];
  const float* Wk  = (const float*)d_in[4];
  const float* bk  = (const float*)d_in[5];
  const float* Wv  = (const float*)d_in[6];
  const float* bv  = (const float*)d_in[7];
  const float* Wo  = (const float*)d_in[8];
  const float* bo  = (const float*)d_in[9];
  const float* W1  = (const float*)d_in[10];
  const float* b1  = (const float*)d_in[11];
  const float* W2  = (const float*)d_in[12];
  const float* b2  = (const float*)d_in[13];
  const float* g1  = (const float*)d_in[14];
  const float* be1 = (const float*)d_in[15];
  const float* g2  = (const float*)d_in[16];
  const float* be2 = (const float*)d_in[17];

  char* ws = (char*)d_ws;
  __hip_bfloat16* xb   = (__hip_bfloat16*)(ws + 33554432);
  __hip_bfloat16* yb   = (__hip_bfloat16*)(ws + 50331648);
  __hip_bfloat16* kqb  = (__hip_bfloat16*)(ws + 67108864);
  __hip_bfloat16* vtb  = (__hip_bfloat16*)(ws + 83886080);
  __hip_bfloat16* ctxb = (__hip_bfloat16*)(ws + 100663296);
  __hip_bfloat16* hb   = (__hip_bfloat16*)(ws + 117440512);     // 67.1 MB
  __hip_bfloat16* wkb  = (__hip_bfloat16*)(ws + 184549376);     // contiguous ->
  __hip_bfloat16* wvb  = (__hip_bfloat16*)(ws + 186646528);
  __hip_bfloat16* wob  = (__hip_bfloat16*)(ws + 188743680);
  __hip_bfloat16* w1b  = (__hip_bfloat16*)(ws + 190840832);
  __hip_bfloat16* w2b  = (__hip_bfloat16*)(ws + 199229440);     // ends 207618048
  // dead-region reuse (per-layer lifetimes):
  __hip_bfloat16* obf = (__hip_bfloat16*)(ws + 67108864);   // over kqb (dead post-fattn)
  __hip_bfloat16* pf0 = (__hip_bfloat16*)(ws + 83886080);   // over vtb (dead post-fattn)
  __hip_bfloat16* pf1 = (__hip_bfloat16*)(ws + 100663296);  // over ctxb (dead post-projO)

  prep_kernel<<<8192, 256, 0, stream>>>((const float4*)q, (const float4*)qa,
                                        (const float4*)pos, (uint2*)xb, (uint2*)yb);
  cast_all_kernel<<<11264, 256, 0, stream>>>(
      (const float4*)Wk, (const float4*)Wv, (const float4*)Wo,
      (const float4*)W1, (const float4*)W2, (uint2*)wkb);

  for (int l = 0; l < L_; ++l) {
    // fused K-proj (z=0, row-major) + V-proj (z=1, vT transposed)
    gemm128_kernel<0,3><<<dim3(4, 128, 2), 256, 0, stream>>>(
        xb, wkb + (size_t)l * 262144, bk + l * 512,
        yb, wvb + (size_t)l * 262144, bv + l * 512,
        kqb, vtb, 512, 512, 512);
    fattn_kernel<<<256, 512, 0, stream>>>(kqb, vtb, frr, ctxb);
    gemm128_kernel<0,0><<<dim3(4, 128, 1), 256, 0, stream>>>(
        ctxb, wob + (size_t)l * 262144, bo + l * 512,
        nullptr, nullptr, nullptr, obf, nullptr, 512, 512, 512);
    // residual + LN1 (bf16 in-place)
    ln_kernel<1,0><<<4096, 256, 0, stream>>>(
        (const uint4*)xb, (const uint4*)obf, nullptr,
        g1 + l * 512, be1 + l * 512, (uint4*)xb, nullptr);
    // FFN1 (ReLU)
    gemm128_kernel<1,0><<<dim3(16, 128, 1), 256, 0, stream>>>(
        xb, w1b + (size_t)l * 1048576, b1 + l * 2048,
        nullptr, nullptr, nullptr, hb, nullptr, 2048, 512, 512);
    // FFN2 split-K=2
    gemm128_kernel<0,0><<<dim3(4, 128, 2), 256, 0, stream>>>(
        hb, w2b + (size_t)l * 1048576, b2 + l * 512,
        nullptr, nullptr, nullptr, pf0, pf1, 512, 2048, 1024);
    // residual + LN2 (bf16 in-place; last layer writes f32 d_out)
    if (l == L_ - 1) {
      ln_kernel<2,1><<<4096, 256, 0, stream>>>(
          (const uint4*)xb, (const uint4*)pf0, (const uint4*)pf1,
          g2 + l * 512, be2 + l * 512, nullptr, (float4*)d_out);
    } else {
      ln_kernel<2,0><<<4096, 256, 0, stream>>>(
          (const uint4*)xb, (const uint4*)pf0, (const uint4*)pf1,
          g2 + l * 512, be2 + l * 512, (uint4*)xb, nullptr);
    }
  }
}